// Round 1
// baseline (3456.462 us; speedup 1.0000x reference)
//
#include <hip/hip_runtime.h>
#include <math.h>

#define LN_EPS 1e-5f

// ---- sortable-uint encoding for float atomicMax ----
__device__ __forceinline__ unsigned f2s(float f) {
    unsigned u = __float_as_uint(f);
    return (u & 0x80000000u) ? ~u : (u | 0x80000000u);
}
__device__ __forceinline__ float s2f(unsigned u) {
    u = (u & 0x80000000u) ? (u & 0x7FFFFFFFu) : ~u;
    return __uint_as_float(u);
}

// ---- fused 4-way projection: out_m = x @ W_m + b_m for m in {q,k,v,s} (blockIdx.y) ----
__global__ __launch_bounds__(256) void proj4_kernel(
    const float* __restrict__ x, int n,
    const float* __restrict__ Wq, const float* __restrict__ bq,
    const float* __restrict__ Wk, const float* __restrict__ bk,
    const float* __restrict__ Wv, const float* __restrict__ bv,
    const float* __restrict__ Ws, const float* __restrict__ bs,
    float* __restrict__ outq, float* __restrict__ outk,
    float* __restrict__ outv, float* __restrict__ outs)
{
    const float* W; const float* b; float* out;
    switch (blockIdx.y) {
        case 0:  W = Wq; b = bq; out = outq; break;
        case 1:  W = Wk; b = bk; out = outk; break;
        case 2:  W = Wv; b = bv; out = outv; break;
        default: W = Ws; b = bs; out = outs; break;
    }
    __shared__ float ws[128 * 128];   // 64 KB
    __shared__ float xs[64 * 128];    // 32 KB
    const int tid = threadIdx.x;
    const int node0 = blockIdx.x * 64;
    int nrows = n - node0; if (nrows > 64) nrows = 64;

    const float4* W4 = (const float4*)W;
    float4* ws4 = (float4*)ws;
    for (int i = tid; i < 128 * 128 / 4; i += 256) ws4[i] = W4[i];
    const float4* x4 = (const float4*)(x + (size_t)node0 * 128);
    float4* xs4 = (float4*)xs;
    for (int i = tid; i < nrows * 32; i += 256) xs4[i] = x4[i];
    __syncthreads();

    const int cg = tid & 15;   // cols cg*8 .. cg*8+7
    const int ng = tid >> 4;   // nodes ng*4 .. ng*4+3
    float acc[4][8];
    #pragma unroll
    for (int i = 0; i < 4; ++i)
        #pragma unroll
        for (int j = 0; j < 8; ++j) acc[i][j] = 0.f;

    #pragma unroll 4
    for (int k = 0; k < 128; ++k) {
        float4 wa = *(const float4*)&ws[k * 128 + cg * 8];
        float4 wb = *(const float4*)&ws[k * 128 + cg * 8 + 4];
        float wv[8] = {wa.x, wa.y, wa.z, wa.w, wb.x, wb.y, wb.z, wb.w};
        #pragma unroll
        for (int i = 0; i < 4; ++i) {
            float xv = xs[(ng * 4 + i) * 128 + k];
            #pragma unroll
            for (int j = 0; j < 8; ++j) acc[i][j] = fmaf(xv, wv[j], acc[i][j]);
        }
    }
    float4 ba = *(const float4*)&b[cg * 8];
    float4 bb = *(const float4*)&b[cg * 8 + 4];
    float bv8[8] = {ba.x, ba.y, ba.z, ba.w, bb.x, bb.y, bb.z, bb.w};
    for (int i = 0; i < 4; ++i) {
        int node = node0 + ng * 4 + i;
        if (node >= n) break;
        float4 o0 = make_float4(acc[i][0] + bv8[0], acc[i][1] + bv8[1],
                                acc[i][2] + bv8[2], acc[i][3] + bv8[3]);
        float4 o1 = make_float4(acc[i][4] + bv8[4], acc[i][5] + bv8[5],
                                acc[i][6] + bv8[6], acc[i][7] + bv8[7]);
        *(float4*)&out[(size_t)node * 128 + cg * 8]     = o0;
        *(float4*)&out[(size_t)node * 128 + cg * 8 + 4] = o1;
    }
}

// ---- per-edge attention logit + segment max (thread = (edge, head)) ----
__global__ __launch_bounds__(256) void alpha_kernel(
    const float* __restrict__ q, const float* __restrict__ k,
    const int* __restrict__ src, const int* __restrict__ dst,
    float* __restrict__ alpha, unsigned* __restrict__ amax, int E)
{
    int t = blockIdx.x * blockDim.x + threadIdx.x;
    if (t >= E * 4) return;
    int e = t >> 2, h = t & 3;
    int s = src[e], d = dst[e];
    const float4* qr = (const float4*)(q + (size_t)d * 128 + h * 32);
    const float4* kr = (const float4*)(k + (size_t)s * 128 + h * 32);
    float sum = 0.f;
    #pragma unroll
    for (int i = 0; i < 8; ++i) {
        float4 a = qr[i], bb = kr[i];
        sum += a.x * bb.x + a.y * bb.y + a.z * bb.z + a.w * bb.w;
    }
    float al = sum * 0.17677669529663687f;  // 1/sqrt(32)
    alpha[t] = al;
    atomicMax(&amax[(size_t)d * 4 + h], f2s(al));
}

// ---- exp(alpha - max) + segment denominator ----
__global__ __launch_bounds__(256) void ex_kernel(
    float* __restrict__ alpha, const unsigned* __restrict__ amax,
    float* __restrict__ denom, const int* __restrict__ dst, int E)
{
    int t = blockIdx.x * blockDim.x + threadIdx.x;
    if (t >= E * 4) return;
    int e = t >> 2, h = t & 3;
    int d = dst[e];
    float m = s2f(amax[(size_t)d * 4 + h]);
    float ex = expf(alpha[t] - m);
    alpha[t] = ex;
    atomicAdd(&denom[(size_t)d * 4 + h], ex);
}

// ---- weighted message scatter: agg[dst] += (ex/denom) * v[src]; 32 threads/edge ----
__global__ __launch_bounds__(256) void scatter_kernel(
    const float* __restrict__ ex, const float* __restrict__ denom,
    const float* __restrict__ v,
    const int* __restrict__ src, const int* __restrict__ dst,
    float* __restrict__ agg, int E)
{
    int t = blockIdx.x * blockDim.x + threadIdx.x;
    int e = t >> 5;
    if (e >= E) return;
    int l = t & 31;          // 32 lanes/edge, 4 dims each
    int h = l >> 3;          // head = dims/32
    int s = src[e], d = dst[e];
    float w = ex[(size_t)e * 4 + h] / denom[(size_t)d * 4 + h];
    float4 vv = *(const float4*)(v + (size_t)s * 128 + l * 4);
    float* ap = agg + (size_t)d * 128 + l * 4;
    atomicAdd(ap + 0, w * vv.x);
    atomicAdd(ap + 1, w * vv.y);
    atomicAdd(ap + 2, w * vv.z);
    atomicAdd(ap + 3, w * vv.w);
}

// ---- layernorm (+ optional relu), one wave per node ----
__global__ __launch_bounds__(256) void ln_kernel(
    const float* __restrict__ in, const float* __restrict__ g,
    const float* __restrict__ b, float* __restrict__ out, int n, int relu)
{
    int node = blockIdx.x * 4 + (threadIdx.x >> 6);
    int lane = threadIdx.x & 63;
    if (node >= n) return;
    const float* row = in + (size_t)node * 128;
    float2 vals = *(const float2*)&row[lane * 2];
    float s = vals.x + vals.y;
    #pragma unroll
    for (int off = 32; off; off >>= 1) s += __shfl_xor(s, off);
    float mu = s * (1.f / 128.f);
    float d0 = vals.x - mu, d1 = vals.y - mu;
    float vs = d0 * d0 + d1 * d1;
    #pragma unroll
    for (int off = 32; off; off >>= 1) vs += __shfl_xor(vs, off);
    float rstd = rsqrtf(vs * (1.f / 128.f) + LN_EPS);
    float o0 = d0 * rstd * g[lane * 2]     + b[lane * 2];
    float o1 = d1 * rstd * g[lane * 2 + 1] + b[lane * 2 + 1];
    if (relu) { o0 = fmaxf(o0, 0.f); o1 = fmaxf(o1, 0.f); }
    *(float2*)&out[(size_t)node * 128 + lane * 2] = make_float2(o0, o1);
}

extern "C" void kernel_launch(void* const* d_in, const int* in_sizes, int n_in,
                              void* d_out, int out_size, void* d_ws, size_t ws_size,
                              hipStream_t stream) {
    const float* x  = (const float*)d_in[0];
    const int*   ei = (const int*)d_in[1];
    const int n = in_sizes[0] / 128;
    const int E = in_sizes[1] / 2;
    const int* src = ei;
    const int* dst = ei + E;

    const float *Wq1 = (const float*)d_in[2],  *bq1 = (const float*)d_in[3];
    const float *Wk1 = (const float*)d_in[4],  *bk1 = (const float*)d_in[5];
    const float *Wv1 = (const float*)d_in[6],  *bv1 = (const float*)d_in[7];
    const float *Ws1 = (const float*)d_in[8],  *bs1 = (const float*)d_in[9];
    const float *g1  = (const float*)d_in[10], *be1 = (const float*)d_in[11];
    const float *Wq2 = (const float*)d_in[12], *bq2 = (const float*)d_in[13];
    const float *Wk2 = (const float*)d_in[14], *bk2 = (const float*)d_in[15];
    const float *Wv2 = (const float*)d_in[16], *bv2 = (const float*)d_in[17];
    const float *Ws2 = (const float*)d_in[18], *bs2 = (const float*)d_in[19];
    const float *g2  = (const float*)d_in[20], *be2 = (const float*)d_in[21];

    // workspace layout
    const size_t nf = (size_t)n * 128;          // node feature matrix elems
    char* w = (char*)d_ws;
    float* q     = (float*)w; w += nf * sizeof(float);
    float* kbuf  = (float*)w; w += nf * sizeof(float);
    float* v     = (float*)w; w += nf * sizeof(float);
    float* agg   = (float*)w; w += nf * sizeof(float);
    float* h     = (float*)w; w += nf * sizeof(float);
    float* alpha = (float*)w; w += (size_t)E * 4 * sizeof(float);
    unsigned* amax = (unsigned*)w; w += (size_t)n * 4 * sizeof(unsigned);
    float* denom   = (float*)w; w += (size_t)n * 4 * sizeof(float);

    dim3 projGrid((n + 63) / 64, 4);
    int ehBlocks = (E * 4 + 255) / 256;
    int scBlocks = (E * 32 + 255) / 256;
    int lnBlocks = (n + 3) / 4;

    // ---------- layer 1 ----------
    hipMemsetAsync(amax, 0, (size_t)n * 4 * sizeof(unsigned), stream);   // f2s-encoded -inf floor
    hipMemsetAsync(denom, 0, (size_t)n * 4 * sizeof(float), stream);
    proj4_kernel<<<projGrid, 256, 0, stream>>>(x, n, Wq1, bq1, Wk1, bk1, Wv1, bv1,
                                               Ws1, bs1, q, kbuf, v, agg);
    alpha_kernel<<<ehBlocks, 256, 0, stream>>>(q, kbuf, src, dst, alpha, amax, E);
    ex_kernel<<<ehBlocks, 256, 0, stream>>>(alpha, amax, denom, dst, E);
    scatter_kernel<<<scBlocks, 256, 0, stream>>>(alpha, denom, v, src, dst, agg, E);
    ln_kernel<<<lnBlocks, 256, 0, stream>>>(agg, g1, be1, h, n, 1);

    // ---------- layer 2 ----------
    hipMemsetAsync(amax, 0, (size_t)n * 4 * sizeof(unsigned), stream);
    hipMemsetAsync(denom, 0, (size_t)n * 4 * sizeof(float), stream);
    proj4_kernel<<<projGrid, 256, 0, stream>>>(h, n, Wq2, bq2, Wk2, bk2, Wv2, bv2,
                                               Ws2, bs2, q, kbuf, v, agg);
    alpha_kernel<<<ehBlocks, 256, 0, stream>>>(q, kbuf, src, dst, alpha, amax, E);
    ex_kernel<<<ehBlocks, 256, 0, stream>>>(alpha, amax, denom, dst, E);
    scatter_kernel<<<scBlocks, 256, 0, stream>>>(alpha, denom, v, src, dst, agg, E);
    ln_kernel<<<lnBlocks, 256, 0, stream>>>(agg, g2, be2, (float*)d_out, n, 0);
}

// Round 2
// 804.919 us; speedup vs baseline: 4.2942x; 4.2942x over previous
//
#include <hip/hip_runtime.h>
#include <math.h>

#define LN_EPS 1e-5f

// ---- fused 4-way projection: out_m = x @ W_m + b_m for m in {q,k,v,s} (blockIdx.y) ----
__global__ __launch_bounds__(256) void proj4_kernel(
    const float* __restrict__ x, int n,
    const float* __restrict__ Wq, const float* __restrict__ bq,
    const float* __restrict__ Wk, const float* __restrict__ bk,
    const float* __restrict__ Wv, const float* __restrict__ bv,
    const float* __restrict__ Ws, const float* __restrict__ bs,
    float* __restrict__ outq, float* __restrict__ outk,
    float* __restrict__ outv, float* __restrict__ outs)
{
    const float* W; const float* b; float* out;
    switch (blockIdx.y) {
        case 0:  W = Wq; b = bq; out = outq; break;
        case 1:  W = Wk; b = bk; out = outk; break;
        case 2:  W = Wv; b = bv; out = outv; break;
        default: W = Ws; b = bs; out = outs; break;
    }
    __shared__ float ws[128 * 128];   // 64 KB
    __shared__ float xs[64 * 128];    // 32 KB
    const int tid = threadIdx.x;
    const int node0 = blockIdx.x * 64;
    int nrows = n - node0; if (nrows > 64) nrows = 64;

    const float4* W4 = (const float4*)W;
    float4* ws4 = (float4*)ws;
    for (int i = tid; i < 128 * 128 / 4; i += 256) ws4[i] = W4[i];
    const float4* x4 = (const float4*)(x + (size_t)node0 * 128);
    float4* xs4 = (float4*)xs;
    for (int i = tid; i < nrows * 32; i += 256) xs4[i] = x4[i];
    __syncthreads();

    const int cg = tid & 15;   // cols cg*8 .. cg*8+7
    const int ng = tid >> 4;   // nodes ng*4 .. ng*4+3
    float acc[4][8];
    #pragma unroll
    for (int i = 0; i < 4; ++i)
        #pragma unroll
        for (int j = 0; j < 8; ++j) acc[i][j] = 0.f;

    #pragma unroll 4
    for (int k = 0; k < 128; ++k) {
        float4 wa = *(const float4*)&ws[k * 128 + cg * 8];
        float4 wb = *(const float4*)&ws[k * 128 + cg * 8 + 4];
        float wv[8] = {wa.x, wa.y, wa.z, wa.w, wb.x, wb.y, wb.z, wb.w};
        #pragma unroll
        for (int i = 0; i < 4; ++i) {
            float xv = xs[(ng * 4 + i) * 128 + k];
            #pragma unroll
            for (int j = 0; j < 8; ++j) acc[i][j] = fmaf(xv, wv[j], acc[i][j]);
        }
    }
    float4 ba = *(const float4*)&b[cg * 8];
    float4 bb = *(const float4*)&b[cg * 8 + 4];
    float bv8[8] = {ba.x, ba.y, ba.z, ba.w, bb.x, bb.y, bb.z, bb.w};
    for (int i = 0; i < 4; ++i) {
        int node = node0 + ng * 4 + i;
        if (node >= n) break;
        float4 o0 = make_float4(acc[i][0] + bv8[0], acc[i][1] + bv8[1],
                                acc[i][2] + bv8[2], acc[i][3] + bv8[3]);
        float4 o1 = make_float4(acc[i][4] + bv8[4], acc[i][5] + bv8[5],
                                acc[i][6] + bv8[6], acc[i][7] + bv8[7]);
        *(float4*)&out[(size_t)node * 128 + cg * 8]     = o0;
        *(float4*)&out[(size_t)node * 128 + cg * 8 + 4] = o1;
    }
}

// ---- CSR build: degree histogram ----
__global__ __launch_bounds__(256) void deg_kernel(
    const int* __restrict__ dst, int* __restrict__ deg, int E)
{
    for (int e = blockIdx.x * blockDim.x + threadIdx.x; e < E;
         e += gridDim.x * blockDim.x)
        atomicAdd(&deg[dst[e]], 1);
}

// ---- CSR build: single-block exclusive scan (n up to ~1M), writes off + cursor ----
__global__ __launch_bounds__(1024) void scan_kernel(
    const int* __restrict__ deg, int* __restrict__ off,
    int* __restrict__ cursor, int n)
{
    __shared__ int sums[1024];
    const int t = threadIdx.x;
    const int CH = (n + 1023) >> 10;
    const int start = t * CH;
    const int end = min(start + CH, n);
    int local = 0;
    for (int i = start; i < end; ++i) local += deg[i];
    sums[t] = local;
    __syncthreads();
    for (int d = 1; d < 1024; d <<= 1) {
        int v = (t >= d) ? sums[t - d] : 0;
        __syncthreads();
        sums[t] += v;
        __syncthreads();
    }
    int run = (t == 0) ? 0 : sums[t - 1];
    for (int i = start; i < end; ++i) {
        off[i] = run; cursor[i] = run;
        run += deg[i];
    }
    if (t == 0) off[n] = sums[1023];
}

// ---- CSR build: fill src lists ----
__global__ __launch_bounds__(256) void fill_kernel(
    const int* __restrict__ src, const int* __restrict__ dst,
    int* __restrict__ cursor, int* __restrict__ csr_src, int E)
{
    for (int e = blockIdx.x * blockDim.x + threadIdx.x; e < E;
         e += gridDim.x * blockDim.x) {
        int d = dst[e];
        int p = atomicAdd(&cursor[d], 1);
        csr_src[p] = src[e];
    }
}

// ---- fused attention + online softmax + skip + layernorm(+relu), one wave/node ----
__global__ __launch_bounds__(256) void attn_ln_kernel(
    const float* __restrict__ q, const float* __restrict__ k,
    const float* __restrict__ v, const float* __restrict__ sp,
    const int* __restrict__ off, const int* __restrict__ csr_src,
    const float* __restrict__ g, const float* __restrict__ b,
    float* __restrict__ out, int n, int relu)
{
    int node = blockIdx.x * 4 + (threadIdx.x >> 6);
    if (node >= n) return;
    int lane = threadIdx.x & 63;

    float2 qv = *(const float2*)(q + (size_t)node * 128 + lane * 2);
    int e0 = off[node], e1 = off[node + 1];

    float m = -INFINITY, ss = 0.f, a0 = 0.f, a1 = 0.f;

    // software-pipelined gather loop
    int scur = (e0 < e1) ? csr_src[e0] : 0;
    float2 kc = make_float2(0.f, 0.f), vc = kc;
    if (e0 < e1) {
        kc = *(const float2*)(k + (size_t)scur * 128 + lane * 2);
        vc = *(const float2*)(v + (size_t)scur * 128 + lane * 2);
    }
    for (int i = e0; i < e1; ++i) {
        int sn = (i + 1 < e1) ? csr_src[i + 1] : scur;
        float2 kn = *(const float2*)(k + (size_t)sn * 128 + lane * 2);
        float2 vn = *(const float2*)(v + (size_t)sn * 128 + lane * 2);

        float dot = qv.x * kc.x + qv.y * kc.y;
        dot += __shfl_xor(dot, 1);
        dot += __shfl_xor(dot, 2);
        dot += __shfl_xor(dot, 4);
        dot += __shfl_xor(dot, 8);
        float al = dot * 0.17677669529663687f;   // 1/sqrt(32)

        float mn = fmaxf(m, al);
        float corr = __expf(m - mn);             // exp(-inf)=0 on first iter
        float w = __expf(al - mn);
        ss = ss * corr + w;
        a0 = a0 * corr + w * vc.x;
        a1 = a1 * corr + w * vc.y;
        m = mn;
        kc = kn; vc = vn;
    }

    float inv = (ss > 0.f) ? 1.f / ss : 0.f;
    float2 sv = *(const float2*)(sp + (size_t)node * 128 + lane * 2);
    float o0 = a0 * inv + sv.x;
    float o1 = a1 * inv + sv.y;

    // layernorm across the wave (128 dims, 2/lane)
    float sum = o0 + o1;
    #pragma unroll
    for (int d = 32; d; d >>= 1) sum += __shfl_xor(sum, d);
    float mu = sum * (1.f / 128.f);
    float d0 = o0 - mu, d1 = o1 - mu;
    float vs = d0 * d0 + d1 * d1;
    #pragma unroll
    for (int d = 32; d; d >>= 1) vs += __shfl_xor(vs, d);
    float rstd = rsqrtf(vs * (1.f / 128.f) + LN_EPS);
    float r0 = d0 * rstd * g[lane * 2]     + b[lane * 2];
    float r1 = d1 * rstd * g[lane * 2 + 1] + b[lane * 2 + 1];
    if (relu) { r0 = fmaxf(r0, 0.f); r1 = fmaxf(r1, 0.f); }
    *(float2*)&out[(size_t)node * 128 + lane * 2] = make_float2(r0, r1);
}

extern "C" void kernel_launch(void* const* d_in, const int* in_sizes, int n_in,
                              void* d_out, int out_size, void* d_ws, size_t ws_size,
                              hipStream_t stream) {
    const float* x  = (const float*)d_in[0];
    const int*   ei = (const int*)d_in[1];
    const int n = in_sizes[0] / 128;
    const int E = in_sizes[1] / 2;
    const int* src = ei;
    const int* dst = ei + E;

    const float *Wq1 = (const float*)d_in[2],  *bq1 = (const float*)d_in[3];
    const float *Wk1 = (const float*)d_in[4],  *bk1 = (const float*)d_in[5];
    const float *Wv1 = (const float*)d_in[6],  *bv1 = (const float*)d_in[7];
    const float *Ws1 = (const float*)d_in[8],  *bs1 = (const float*)d_in[9];
    const float *g1  = (const float*)d_in[10], *be1 = (const float*)d_in[11];
    const float *Wq2 = (const float*)d_in[12], *bq2 = (const float*)d_in[13];
    const float *Wk2 = (const float*)d_in[14], *bk2 = (const float*)d_in[15];
    const float *Wv2 = (const float*)d_in[16], *bv2 = (const float*)d_in[17];
    const float *Ws2 = (const float*)d_in[18], *bs2 = (const float*)d_in[19];
    const float *g2  = (const float*)d_in[20], *be2 = (const float*)d_in[21];

    // workspace layout
    const size_t nf = (size_t)n * 128;
    char* w = (char*)d_ws;
    float* q    = (float*)w; w += nf * sizeof(float);
    float* kbuf = (float*)w; w += nf * sizeof(float);
    float* v    = (float*)w; w += nf * sizeof(float);
    float* sp   = (float*)w; w += nf * sizeof(float);
    float* h    = (float*)w; w += nf * sizeof(float);
    int* deg     = (int*)w; w += (size_t)(n + 1) * sizeof(int);
    int* off     = (int*)w; w += (size_t)(n + 1) * sizeof(int);
    int* cursor  = (int*)w; w += (size_t)(n + 1) * sizeof(int);
    int* csr_src = (int*)w; w += (size_t)E * sizeof(int);

    dim3 projGrid((n + 63) / 64, 4);
    int edgeBlocks = (E + 255) / 256; if (edgeBlocks > 2048) edgeBlocks = 2048;
    int nodeBlocks = (n + 3) / 4;

    // ---------- CSR build (graph shared by both layers) ----------
    hipMemsetAsync(deg, 0, (size_t)n * sizeof(int), stream);
    deg_kernel<<<edgeBlocks, 256, 0, stream>>>(dst, deg, E);
    scan_kernel<<<1, 1024, 0, stream>>>(deg, off, cursor, n);
    fill_kernel<<<edgeBlocks, 256, 0, stream>>>(src, dst, cursor, csr_src, E);

    // ---------- layer 1 ----------
    proj4_kernel<<<projGrid, 256, 0, stream>>>(x, n, Wq1, bq1, Wk1, bk1, Wv1, bv1,
                                               Ws1, bs1, q, kbuf, v, sp);
    attn_ln_kernel<<<nodeBlocks, 256, 0, stream>>>(q, kbuf, v, sp, off, csr_src,
                                                   g1, be1, h, n, 1);

    // ---------- layer 2 ----------
    proj4_kernel<<<projGrid, 256, 0, stream>>>(h, n, Wq2, bq2, Wk2, bk2, Wv2, bv2,
                                               Ws2, bs2, q, kbuf, v, sp);
    attn_ln_kernel<<<nodeBlocks, 256, 0, stream>>>(q, kbuf, v, sp, off, csr_src,
                                                   g2, be2, (float*)d_out, n, 0);
}

// Round 3
// 540.006 us; speedup vs baseline: 6.4008x; 1.4906x over previous
//
#include <hip/hip_runtime.h>
#include <math.h>

#define LN_EPS 1e-5f

typedef __attribute__((ext_vector_type(8))) short bf16x8;
typedef __attribute__((ext_vector_type(4))) float f32x4;

__device__ __forceinline__ unsigned short f2b(float f) {
    unsigned u = __float_as_uint(f);
    unsigned r = (u + 0x7FFFu + ((u >> 16) & 1)) >> 16;   // RNE
    return (unsigned short)r;
}

// ---- convert fp32 [rows][128] -> bf16 MFMA-A-fragment order xf[rb][t][lane][8] ----
// A-frag (16x16x32): lane l holds A[rb*16 + (l&15)][t*32 + 8*(l>>4) + j], j=0..7
__global__ __launch_bounds__(256) void convert_frag_kernel(
    const float* __restrict__ x, unsigned short* __restrict__ xf,
    int n, int total)
{
    int t = blockIdx.x * 256 + threadIdx.x;   // t = r*16 + c  (c = 8-elem chunk)
    if (t >= total) return;
    int r = t >> 4, c = t & 15;
    float v[8];
    if (r < n) {
        float4 a = *(const float4*)(x + (size_t)r * 128 + c * 8);
        float4 b = *(const float4*)(x + (size_t)r * 128 + c * 8 + 4);
        v[0]=a.x; v[1]=a.y; v[2]=a.z; v[3]=a.w; v[4]=b.x; v[5]=b.y; v[6]=b.z; v[7]=b.w;
    } else {
        #pragma unroll
        for (int j = 0; j < 8; ++j) v[j] = 0.f;
    }
    int rb = r >> 4, rr = r & 15, tk = c >> 2, hi = c & 3;
    int lane = hi * 16 + rr;
    union { bf16x8 vec; unsigned short u[8]; } o;
    #pragma unroll
    for (int j = 0; j < 8; ++j) o.u[j] = f2b(v[j]);
    *(bf16x8*)(xf + ((((size_t)rb * 4 + tk) * 64 + lane) * 8)) = o.vec;
}

// ---- convert 8 weight matrices [128k][128n] -> B-fragment order wf[mi][cb][t][lane][8] ----
// B-frag: lane l holds W[t*32 + 8*(l>>4) + j][cb*16 + (l&15)]
__global__ __launch_bounds__(256) void convert_w_kernel(
    const float* __restrict__ W0, const float* __restrict__ W1,
    const float* __restrict__ W2, const float* __restrict__ W3,
    const float* __restrict__ W4, const float* __restrict__ W5,
    const float* __restrict__ W6, const float* __restrict__ W7,
    unsigned short* __restrict__ wf)
{
    int t = blockIdx.x * 256 + threadIdx.x;   // 16384 threads: [mi][cb][tk][lane]
    if (t >= 16384) return;
    int mi = t >> 11, cb = (t >> 8) & 7, tk = (t >> 6) & 3, lane = t & 63;
    const float* W;
    switch (mi) {
        case 0: W = W0; break; case 1: W = W1; break;
        case 2: W = W2; break; case 3: W = W3; break;
        case 4: W = W4; break; case 5: W = W5; break;
        case 6: W = W6; break; default: W = W7; break;
    }
    int hi = lane >> 4, c = lane & 15;
    int col = cb * 16 + c;
    union { bf16x8 vec; unsigned short u[8]; } o;
    #pragma unroll
    for (int j = 0; j < 8; ++j) {
        int k = tk * 32 + hi * 8 + j;
        o.u[j] = f2b(W[k * 128 + col]);
    }
    *(bf16x8*)(wf + (size_t)t * 8) = o.vec;
}

// ---- MFMA projection: out_mi = x @ W_mi + b_mi, no LDS, frag loads from global ----
__global__ __launch_bounds__(256) void proj_mfma_kernel(
    const unsigned short* __restrict__ xf, const unsigned short* __restrict__ wf,
    const float* __restrict__ b0, const float* __restrict__ b1,
    const float* __restrict__ b2, const float* __restrict__ b3,
    float* __restrict__ o0, float* __restrict__ o1,
    float* __restrict__ o2, float* __restrict__ o3,
    int n)
{
    int mi = blockIdx.y;
    const float* bias; float* out;
    switch (mi) {
        case 0: bias = b0; out = o0; break;
        case 1: bias = b1; out = o1; break;
        case 2: bias = b2; out = o2; break;
        default: bias = b3; out = o3; break;
    }
    const bf16x8* xfv = (const bf16x8*)xf;
    const bf16x8* wfv = (const bf16x8*)(wf + (size_t)mi * 16384);

    int wave = threadIdx.x >> 6, lane = threadIdx.x & 63;
    int rb0 = (blockIdx.x * 4 + wave) * 2;   // two 16-row blocks per wave

    bf16x8 af[2][4];
    #pragma unroll
    for (int rb2 = 0; rb2 < 2; ++rb2)
        #pragma unroll
        for (int t = 0; t < 4; ++t)
            af[rb2][t] = xfv[((size_t)(rb0 + rb2) * 4 + t) * 64 + lane];

    int c = lane & 15, rowg = (lane >> 4) * 4;
    int r0 = rb0 * 16 + rowg;

    #pragma unroll
    for (int cb = 0; cb < 8; ++cb) {
        f32x4 acc0 = {0.f, 0.f, 0.f, 0.f};
        f32x4 acc1 = {0.f, 0.f, 0.f, 0.f};
        #pragma unroll
        for (int t = 0; t < 4; ++t) {
            bf16x8 bfr = wfv[(cb * 4 + t) * 64 + lane];
            acc0 = __builtin_amdgcn_mfma_f32_16x16x32_bf16(af[0][t], bfr, acc0, 0, 0, 0);
            acc1 = __builtin_amdgcn_mfma_f32_16x16x32_bf16(af[1][t], bfr, acc1, 0, 0, 0);
        }
        int col = cb * 16 + c;
        float bb = bias[col];
        #pragma unroll
        for (int reg = 0; reg < 4; ++reg) {
            int ra = r0 + reg;
            if (ra < n)      out[(size_t)ra * 128 + col]        = acc0[reg] + bb;
            if (ra + 16 < n) out[(size_t)(ra + 16) * 128 + col] = acc1[reg] + bb;
        }
    }
}

// ---- CSR build: degree histogram ----
__global__ __launch_bounds__(256) void deg_kernel(
    const int* __restrict__ dst, int* __restrict__ deg, int E)
{
    for (int e = blockIdx.x * blockDim.x + threadIdx.x; e < E;
         e += gridDim.x * blockDim.x)
        atomicAdd(&deg[dst[e]], 1);
}

// ---- CSR build: single-block exclusive scan ----
__global__ __launch_bounds__(1024) void scan_kernel(
    const int* __restrict__ deg, int* __restrict__ off,
    int* __restrict__ cursor, int n)
{
    __shared__ int sums[1024];
    const int t = threadIdx.x;
    const int CH = (n + 1023) >> 10;
    const int start = t * CH;
    const int end = min(start + CH, n);
    int local = 0;
    for (int i = start; i < end; ++i) local += deg[i];
    sums[t] = local;
    __syncthreads();
    for (int d = 1; d < 1024; d <<= 1) {
        int v = (t >= d) ? sums[t - d] : 0;
        __syncthreads();
        sums[t] += v;
        __syncthreads();
    }
    int run = (t == 0) ? 0 : sums[t - 1];
    for (int i = start; i < end; ++i) {
        off[i] = run; cursor[i] = run;
        run += deg[i];
    }
    if (t == 0) off[n] = sums[1023];
}

// ---- CSR build: fill src lists ----
__global__ __launch_bounds__(256) void fill_kernel(
    const int* __restrict__ src, const int* __restrict__ dst,
    int* __restrict__ cursor, int* __restrict__ csr_src, int E)
{
    for (int e = blockIdx.x * blockDim.x + threadIdx.x; e < E;
         e += gridDim.x * blockDim.x) {
        int d = dst[e];
        int p = atomicAdd(&cursor[d], 1);
        csr_src[p] = src[e];
    }
}

// ---- fused attention + online softmax + skip + layernorm(+relu), one wave/node ----
__global__ __launch_bounds__(256) void attn_ln_kernel(
    const float* __restrict__ q, const float* __restrict__ k,
    const float* __restrict__ v, const float* __restrict__ sp,
    const int* __restrict__ off, const int* __restrict__ csr_src,
    const float* __restrict__ g, const float* __restrict__ b,
    float* __restrict__ out, int n, int relu)
{
    int node = blockIdx.x * 4 + (threadIdx.x >> 6);
    if (node >= n) return;
    int lane = threadIdx.x & 63;

    float2 qv = *(const float2*)(q + (size_t)node * 128 + lane * 2);
    int e0 = off[node], e1 = off[node + 1];

    float m = -INFINITY, ss = 0.f, a0 = 0.f, a1 = 0.f;

    int scur = (e0 < e1) ? csr_src[e0] : 0;
    float2 kc = make_float2(0.f, 0.f), vc = kc;
    if (e0 < e1) {
        kc = *(const float2*)(k + (size_t)scur * 128 + lane * 2);
        vc = *(const float2*)(v + (size_t)scur * 128 + lane * 2);
    }
    for (int i = e0; i < e1; ++i) {
        int sn = (i + 1 < e1) ? csr_src[i + 1] : scur;
        float2 kn = *(const float2*)(k + (size_t)sn * 128 + lane * 2);
        float2 vn = *(const float2*)(v + (size_t)sn * 128 + lane * 2);

        float dot = qv.x * kc.x + qv.y * kc.y;
        dot += __shfl_xor(dot, 1);
        dot += __shfl_xor(dot, 2);
        dot += __shfl_xor(dot, 4);
        dot += __shfl_xor(dot, 8);
        float al = dot * 0.17677669529663687f;   // 1/sqrt(32)

        float mn = fmaxf(m, al);
        float corr = __expf(m - mn);
        float w = __expf(al - mn);
        ss = ss * corr + w;
        a0 = a0 * corr + w * vc.x;
        a1 = a1 * corr + w * vc.y;
        m = mn;
        kc = kn; vc = vn;
    }

    float inv = (ss > 0.f) ? 1.f / ss : 0.f;
    float2 sv = *(const float2*)(sp + (size_t)node * 128 + lane * 2);
    float o0 = a0 * inv + sv.x;
    float o1 = a1 * inv + sv.y;

    float sum = o0 + o1;
    #pragma unroll
    for (int d = 32; d; d >>= 1) sum += __shfl_xor(sum, d);
    float mu = sum * (1.f / 128.f);
    float d0 = o0 - mu, d1 = o1 - mu;
    float vs = d0 * d0 + d1 * d1;
    #pragma unroll
    for (int d = 32; d; d >>= 1) vs += __shfl_xor(vs, d);
    float rstd = rsqrtf(vs * (1.f / 128.f) + LN_EPS);
    float r0 = d0 * rstd * g[lane * 2]     + b[lane * 2];
    float r1 = d1 * rstd * g[lane * 2 + 1] + b[lane * 2 + 1];
    if (relu) { r0 = fmaxf(r0, 0.f); r1 = fmaxf(r1, 0.f); }
    *(float2*)&out[(size_t)node * 128 + lane * 2] = make_float2(r0, r1);
}

extern "C" void kernel_launch(void* const* d_in, const int* in_sizes, int n_in,
                              void* d_out, int out_size, void* d_ws, size_t ws_size,
                              hipStream_t stream) {
    const float* x  = (const float*)d_in[0];
    const int*   ei = (const int*)d_in[1];
    const int n = in_sizes[0] / 128;
    const int E = in_sizes[1] / 2;
    const int* src = ei;
    const int* dst = ei + E;

    const float *Wq1 = (const float*)d_in[2],  *bq1 = (const float*)d_in[3];
    const float *Wk1 = (const float*)d_in[4],  *bk1 = (const float*)d_in[5];
    const float *Wv1 = (const float*)d_in[6],  *bv1 = (const float*)d_in[7];
    const float *Ws1 = (const float*)d_in[8],  *bs1 = (const float*)d_in[9];
    const float *g1  = (const float*)d_in[10], *be1 = (const float*)d_in[11];
    const float *Wq2 = (const float*)d_in[12], *bq2 = (const float*)d_in[13];
    const float *Wk2 = (const float*)d_in[14], *bk2 = (const float*)d_in[15];
    const float *Wv2 = (const float*)d_in[16], *bv2 = (const float*)d_in[17];
    const float *Ws2 = (const float*)d_in[18], *bs2 = (const float*)d_in[19];
    const float *g2  = (const float*)d_in[20], *be2 = (const float*)d_in[21];

    // geometry
    const int nrb   = (n + 15) / 16;            // real rowblocks
    const int nblk  = (nrb + 7) / 8;            // proj grid.x (8 rowblocks/block)
    const int padrb = nblk * 8;                 // padded rowblocks in xf

    // workspace layout
    const size_t nf = (size_t)n * 128;
    char* w = (char*)d_ws;
    float* q    = (float*)w; w += nf * sizeof(float);
    float* kbuf = (float*)w; w += nf * sizeof(float);
    float* v    = (float*)w; w += nf * sizeof(float);
    float* sp   = (float*)w; w += nf * sizeof(float);
    unsigned short* xf = (unsigned short*)w; w += (size_t)padrb * 2048 * sizeof(unsigned short);
    unsigned short* wf = (unsigned short*)w; w += (size_t)8 * 16384 * sizeof(unsigned short);
    int* deg     = (int*)w; w += (size_t)(n + 1) * sizeof(int);
    int* off     = (int*)w; w += (size_t)(n + 1) * sizeof(int);
    int* cursor  = (int*)w; w += (size_t)(n + 1) * sizeof(int);
    int* csr_src = (int*)w; w += (size_t)E * sizeof(int);
    float* h = (float*)d_out;                   // layer-1 hidden lives in d_out

    dim3 projGrid(nblk, 4);
    int edgeBlocks = (E + 255) / 256; if (edgeBlocks > 2048) edgeBlocks = 2048;
    int nodeBlocks = (n + 3) / 4;
    int cvTotal = padrb * 256;                  // (padrb*16 rows) * 16 chunks
    int cvBlocks = (cvTotal + 255) / 256;

    // ---------- one-time prep ----------
    convert_w_kernel<<<64, 256, 0, stream>>>(Wq1, Wk1, Wv1, Ws1, Wq2, Wk2, Wv2, Ws2, wf);
    hipMemsetAsync(deg, 0, (size_t)n * sizeof(int), stream);
    deg_kernel<<<edgeBlocks, 256, 0, stream>>>(dst, deg, E);
    scan_kernel<<<1, 1024, 0, stream>>>(deg, off, cursor, n);
    fill_kernel<<<edgeBlocks, 256, 0, stream>>>(src, dst, cursor, csr_src, E);

    // ---------- layer 1 ----------
    convert_frag_kernel<<<cvBlocks, 256, 0, stream>>>(x, xf, n, cvTotal);
    proj_mfma_kernel<<<projGrid, 256, 0, stream>>>(xf, wf, bq1, bk1, bv1, bs1,
                                                   q, kbuf, v, sp, n);
    attn_ln_kernel<<<nodeBlocks, 256, 0, stream>>>(q, kbuf, v, sp, off, csr_src,
                                                   g1, be1, h, n, 1);

    // ---------- layer 2 ----------
    convert_frag_kernel<<<cvBlocks, 256, 0, stream>>>(h, xf, n, cvTotal);
    proj_mfma_kernel<<<projGrid, 256, 0, stream>>>(xf, wf + (size_t)4 * 16384,
                                                   bq2, bk2, bv2, bs2,
                                                   q, kbuf, v, sp, n);
    attn_ln_kernel<<<nodeBlocks, 256, 0, stream>>>(q, kbuf, v, sp, off, csr_src,
                                                   g2, be2, (float*)d_out, n, 0);
}

// Round 4
// 460.839 us; speedup vs baseline: 7.5004x; 1.1718x over previous
//
#include <hip/hip_runtime.h>
#include <math.h>

#define LN_EPS 1e-5f

typedef __attribute__((ext_vector_type(8))) short bf16x8;
typedef __attribute__((ext_vector_type(4))) float f32x4;

__device__ __forceinline__ unsigned short f2b(float f) {
    unsigned u = __float_as_uint(f);
    unsigned r = (u + 0x7FFFu + ((u >> 16) & 1)) >> 16;   // RNE
    return (unsigned short)r;
}

// ---- convert fp32 [n][128] -> bf16 row-major [padrows][128], zero-padded ----
__global__ __launch_bounds__(256) void convert_xb_kernel(
    const float* __restrict__ x, unsigned short* __restrict__ xb,
    int n, int total)   // total = padrows*16 (threads; 8 elems each)
{
    int t = blockIdx.x * 256 + threadIdx.x;
    if (t >= total) return;
    int r = t >> 4, c = t & 15;
    union { bf16x8 vec; unsigned short u[8]; } o;
    if (r < n) {
        float4 a = *(const float4*)(x + (size_t)r * 128 + c * 8);
        float4 b = *(const float4*)(x + (size_t)r * 128 + c * 8 + 4);
        o.u[0]=f2b(a.x); o.u[1]=f2b(a.y); o.u[2]=f2b(a.z); o.u[3]=f2b(a.w);
        o.u[4]=f2b(b.x); o.u[5]=f2b(b.y); o.u[6]=f2b(b.z); o.u[7]=f2b(b.w);
    } else {
        #pragma unroll
        for (int j = 0; j < 8; ++j) o.u[j] = 0;
    }
    *(bf16x8*)(xb + (size_t)r * 128 + c * 8) = o.vec;
}

// ---- convert 8 weight matrices [128k][128n] -> B-fragment order wf[mi][cb][t][lane][8] ----
__global__ __launch_bounds__(256) void convert_w_kernel(
    const float* __restrict__ W0, const float* __restrict__ W1,
    const float* __restrict__ W2, const float* __restrict__ W3,
    const float* __restrict__ W4, const float* __restrict__ W5,
    const float* __restrict__ W6, const float* __restrict__ W7,
    unsigned short* __restrict__ wf)
{
    int t = blockIdx.x * 256 + threadIdx.x;   // [mi][cb][tk][lane]
    if (t >= 16384) return;
    int mi = t >> 11, cb = (t >> 8) & 7, tk = (t >> 6) & 3, lane = t & 63;
    const float* W;
    switch (mi) {
        case 0: W = W0; break; case 1: W = W1; break;
        case 2: W = W2; break; case 3: W = W3; break;
        case 4: W = W4; break; case 5: W = W5; break;
        case 6: W = W6; break; default: W = W7; break;
    }
    int hi = lane >> 4, c = lane & 15;
    int col = cb * 16 + c;
    union { bf16x8 vec; unsigned short u[8]; } o;
    #pragma unroll
    for (int j = 0; j < 8; ++j) {
        int k = tk * 32 + hi * 8 + j;
        o.u[j] = f2b(W[k * 128 + col]);
    }
    *(bf16x8*)(wf + (size_t)t * 8) = o.vec;
}

// ---- MFMA projection from row-major bf16 xb; q/sp fp32, k/v interleaved bf16 ----
__global__ __launch_bounds__(256) void proj_mfma_kernel(
    const unsigned short* __restrict__ xb, const unsigned short* __restrict__ wf,
    const float* __restrict__ b0, const float* __restrict__ b1,
    const float* __restrict__ b2, const float* __restrict__ b3,
    float* __restrict__ qout, unsigned short* __restrict__ kvb,
    float* __restrict__ spout, int n)
{
    int mi = blockIdx.y;
    const float* bias;
    switch (mi) {
        case 0: bias = b0; break;
        case 1: bias = b1; break;
        case 2: bias = b2; break;
        default: bias = b3; break;
    }
    const bf16x8* wfv = (const bf16x8*)(wf + (size_t)mi * 16384);

    int wave = threadIdx.x >> 6, lane = threadIdx.x & 63;
    int rb0 = (blockIdx.x * 4 + wave) * 2;
    int rr = lane & 15, hi = lane >> 4;

    // A-fragment loads straight from row-major bf16: 16B contiguous per lane
    bf16x8 af[2][4];
    #pragma unroll
    for (int rb2 = 0; rb2 < 2; ++rb2) {
        int row = (rb0 + rb2) * 16 + rr;
        #pragma unroll
        for (int t = 0; t < 4; ++t)
            af[rb2][t] = *(const bf16x8*)(xb + (size_t)row * 128 + t * 32 + hi * 8);
    }

    int c = lane & 15, rowg = (lane >> 4) * 4;
    int r0 = rb0 * 16 + rowg;

    #pragma unroll
    for (int cb = 0; cb < 8; ++cb) {
        f32x4 acc0 = {0.f, 0.f, 0.f, 0.f};
        f32x4 acc1 = {0.f, 0.f, 0.f, 0.f};
        #pragma unroll
        for (int t = 0; t < 4; ++t) {
            bf16x8 bfr = wfv[(cb * 4 + t) * 64 + lane];
            acc0 = __builtin_amdgcn_mfma_f32_16x16x32_bf16(af[0][t], bfr, acc0, 0, 0, 0);
            acc1 = __builtin_amdgcn_mfma_f32_16x16x32_bf16(af[1][t], bfr, acc1, 0, 0, 0);
        }
        int col = cb * 16 + c;
        float bb = bias[col];
        #pragma unroll
        for (int reg = 0; reg < 4; ++reg) {
            #pragma unroll
            for (int half = 0; half < 2; ++half) {
                int ra = r0 + reg + half * 16;
                if (ra >= n) continue;
                float val = (half ? acc1[reg] : acc0[reg]) + bb;
                if (mi == 0)      qout[(size_t)ra * 128 + col] = val;
                else if (mi == 3) spout[(size_t)ra * 128 + col] = val;
                else if (mi == 1) kvb[(size_t)ra * 256 + col * 2]     = f2b(val);
                else              kvb[(size_t)ra * 256 + col * 2 + 1] = f2b(val);
            }
        }
    }
}

// ---- CSR build ----
__global__ __launch_bounds__(256) void deg_kernel(
    const int* __restrict__ dst, int* __restrict__ deg, int E)
{
    for (int e = blockIdx.x * blockDim.x + threadIdx.x; e < E;
         e += gridDim.x * blockDim.x)
        atomicAdd(&deg[dst[e]], 1);
}

__global__ __launch_bounds__(1024) void scan_kernel(
    const int* __restrict__ deg, int* __restrict__ off,
    int* __restrict__ cursor, int n)
{
    __shared__ int sums[1024];
    const int t = threadIdx.x;
    const int CH = (n + 1023) >> 10;
    const int start = t * CH;
    const int end = min(start + CH, n);
    int local = 0;
    for (int i = start; i < end; ++i) local += deg[i];
    sums[t] = local;
    __syncthreads();
    for (int d = 1; d < 1024; d <<= 1) {
        int v = (t >= d) ? sums[t - d] : 0;
        __syncthreads();
        sums[t] += v;
        __syncthreads();
    }
    int run = (t == 0) ? 0 : sums[t - 1];
    for (int i = start; i < end; ++i) {
        off[i] = run; cursor[i] = run;
        run += deg[i];
    }
    if (t == 0) off[n] = sums[1023];
}

__global__ __launch_bounds__(256) void fill_kernel(
    const int* __restrict__ src, const int* __restrict__ dst,
    int* __restrict__ cursor, int* __restrict__ csr_src, int E)
{
    for (int e = blockIdx.x * blockDim.x + threadIdx.x; e < E;
         e += gridDim.x * blockDim.x) {
        int d = dst[e];
        int p = atomicAdd(&cursor[d], 1);
        csr_src[p] = src[e];
    }
}

// ---- fused attention + online softmax + skip + LN; one wave/node ----
// relu=1: write bf16 row-major hb (layer-1 hidden). relu=0: write fp32 outf.
__global__ __launch_bounds__(256) void attn_ln_kernel(
    const float* __restrict__ q, const uint2* __restrict__ kvp,
    const float* __restrict__ sp,
    const int* __restrict__ off, const int* __restrict__ csr_src,
    const float* __restrict__ g, const float* __restrict__ b,
    float* __restrict__ outf, unsigned int* __restrict__ outb,
    int n, int relu)
{
    int node = blockIdx.x * 4 + (threadIdx.x >> 6);
    if (node >= n) return;
    int lane = threadIdx.x & 63;

    float2 qv = *(const float2*)(q + (size_t)node * 128 + lane * 2);
    int e0 = off[node], e1 = off[node + 1];

    float m = -INFINITY, ss = 0.f, a0 = 0.f, a1 = 0.f;

    int scur = (e0 < e1) ? csr_src[e0] : 0;
    uint2 kvc = make_uint2(0u, 0u);
    if (e0 < e1) kvc = kvp[(size_t)scur * 64 + lane];

    for (int i = e0; i < e1; ++i) {
        int sn = (i + 1 < e1) ? csr_src[i + 1] : scur;
        uint2 kvn = kvp[(size_t)sn * 64 + lane];

        float k0 = __uint_as_float(kvc.x << 16);
        float v0 = __uint_as_float(kvc.x & 0xFFFF0000u);
        float k1 = __uint_as_float(kvc.y << 16);
        float v1 = __uint_as_float(kvc.y & 0xFFFF0000u);

        float dot = qv.x * k0 + qv.y * k1;
        dot += __shfl_xor(dot, 1);
        dot += __shfl_xor(dot, 2);
        dot += __shfl_xor(dot, 4);
        dot += __shfl_xor(dot, 8);
        float al = dot * 0.17677669529663687f;   // 1/sqrt(32)

        float mn = fmaxf(m, al);
        float corr = __expf(m - mn);
        float w = __expf(al - mn);
        ss = ss * corr + w;
        a0 = a0 * corr + w * v0;
        a1 = a1 * corr + w * v1;
        m = mn;
        kvc = kvn;
    }

    float inv = (ss > 0.f) ? 1.f / ss : 0.f;
    float2 sv = *(const float2*)(sp + (size_t)node * 128 + lane * 2);
    float o0 = a0 * inv + sv.x;
    float o1 = a1 * inv + sv.y;

    float sum = o0 + o1;
    #pragma unroll
    for (int d = 32; d; d >>= 1) sum += __shfl_xor(sum, d);
    float mu = sum * (1.f / 128.f);
    float d0 = o0 - mu, d1 = o1 - mu;
    float vs = d0 * d0 + d1 * d1;
    #pragma unroll
    for (int d = 32; d; d >>= 1) vs += __shfl_xor(vs, d);
    float rstd = rsqrtf(vs * (1.f / 128.f) + LN_EPS);
    float r0 = d0 * rstd * g[lane * 2]     + b[lane * 2];
    float r1 = d1 * rstd * g[lane * 2 + 1] + b[lane * 2 + 1];
    if (relu) {
        r0 = fmaxf(r0, 0.f); r1 = fmaxf(r1, 0.f);
        outb[(size_t)node * 64 + lane] =
            (unsigned)f2b(r0) | ((unsigned)f2b(r1) << 16);
    } else {
        *(float2*)&outf[(size_t)node * 128 + lane * 2] = make_float2(r0, r1);
    }
}

extern "C" void kernel_launch(void* const* d_in, const int* in_sizes, int n_in,
                              void* d_out, int out_size, void* d_ws, size_t ws_size,
                              hipStream_t stream) {
    const float* x  = (const float*)d_in[0];
    const int*   ei = (const int*)d_in[1];
    const int n = in_sizes[0] / 128;
    const int E = in_sizes[1] / 2;
    const int* src = ei;
    const int* dst = ei + E;

    const float *Wq1 = (const float*)d_in[2],  *bq1 = (const float*)d_in[3];
    const float *Wk1 = (const float*)d_in[4],  *bk1 = (const float*)d_in[5];
    const float *Wv1 = (const float*)d_in[6],  *bv1 = (const float*)d_in[7];
    const float *Ws1 = (const float*)d_in[8],  *bs1 = (const float*)d_in[9];
    const float *g1  = (const float*)d_in[10], *be1 = (const float*)d_in[11];
    const float *Wq2 = (const float*)d_in[12], *bq2 = (const float*)d_in[13];
    const float *Wk2 = (const float*)d_in[14], *bk2 = (const float*)d_in[15];
    const float *Wv2 = (const float*)d_in[16], *bv2 = (const float*)d_in[17];
    const float *Ws2 = (const float*)d_in[18], *bs2 = (const float*)d_in[19];
    const float *g2  = (const float*)d_in[20], *be2 = (const float*)d_in[21];

    // geometry
    const int nrb    = (n + 15) / 16;
    const int nblk   = (nrb + 7) / 8;
    const int padrows = nblk * 8 * 16;

    // workspace layout
    const size_t nf = (size_t)n * 128;
    char* w = (char*)d_ws;
    float* q  = (float*)w; w += nf * sizeof(float);
    float* sp = (float*)w; w += nf * sizeof(float);
    unsigned short* kvb = (unsigned short*)w; w += (size_t)n * 256 * sizeof(unsigned short);
    unsigned short* xb  = (unsigned short*)w; w += (size_t)padrows * 128 * sizeof(unsigned short);
    unsigned short* hb  = (unsigned short*)w; w += (size_t)padrows * 128 * sizeof(unsigned short);
    unsigned short* wf  = (unsigned short*)w; w += (size_t)8 * 16384 * sizeof(unsigned short);
    int* deg     = (int*)w; w += (size_t)(n + 1) * sizeof(int);
    int* off     = (int*)w; w += (size_t)(n + 1) * sizeof(int);
    int* cursor  = (int*)w; w += (size_t)(n + 1) * sizeof(int);
    int* csr_src = (int*)w; w += (size_t)E * sizeof(int);

    dim3 projGrid(nblk, 4);
    int edgeBlocks = (E + 255) / 256; if (edgeBlocks > 2048) edgeBlocks = 2048;
    int nodeBlocks = (n + 3) / 4;
    int cvTotal  = padrows * 16;
    int cvBlocks = (cvTotal + 255) / 256;

    // ---------- one-time prep ----------
    convert_w_kernel<<<64, 256, 0, stream>>>(Wq1, Wk1, Wv1, Ws1, Wq2, Wk2, Wv2, Ws2, wf);
    hipMemsetAsync(deg, 0, (size_t)n * sizeof(int), stream);
    deg_kernel<<<edgeBlocks, 256, 0, stream>>>(dst, deg, E);
    scan_kernel<<<1, 1024, 0, stream>>>(deg, off, cursor, n);
    fill_kernel<<<edgeBlocks, 256, 0, stream>>>(src, dst, cursor, csr_src, E);
    convert_xb_kernel<<<cvBlocks, 256, 0, stream>>>(x, xb, n, cvTotal);

    // ---------- layer 1 ----------
    proj_mfma_kernel<<<projGrid, 256, 0, stream>>>(xb, wf, bq1, bk1, bv1, bs1,
                                                   q, kvb, sp, n);
    attn_ln_kernel<<<nodeBlocks, 256, 0, stream>>>(q, (const uint2*)kvb, sp,
                                                   off, csr_src, g1, be1,
                                                   nullptr, (unsigned int*)hb, n, 1);

    // ---------- layer 2 ----------
    proj_mfma_kernel<<<projGrid, 256, 0, stream>>>(hb, wf + (size_t)4 * 16384,
                                                   bq2, bk2, bv2, bs2,
                                                   q, kvb, sp, n);
    attn_ln_kernel<<<nodeBlocks, 256, 0, stream>>>(q, (const uint2*)kvb, sp,
                                                   off, csr_src, g2, be2,
                                                   (float*)d_out, nullptr, n, 0);
}

// Round 5
// 355.406 us; speedup vs baseline: 9.7254x; 1.2967x over previous
//
#include <hip/hip_runtime.h>
#include <math.h>

#define LN_EPS 1e-5f

typedef __attribute__((ext_vector_type(8))) short bf16x8;
typedef __attribute__((ext_vector_type(4))) float f32x4;

__device__ __forceinline__ unsigned short f2b(float f) {
    unsigned u = __float_as_uint(f);
    unsigned r = (u + 0x7FFFu + ((u >> 16) & 1)) >> 16;   // RNE
    return (unsigned short)r;
}

// ---- convert fp32 [n][128] -> bf16 row-major [padrows][128], zero-padded ----
__global__ __launch_bounds__(256) void convert_xb_kernel(
    const float* __restrict__ x, unsigned short* __restrict__ xb,
    int n, int total)   // total = padrows*16 (threads; 8 elems each)
{
    int t = blockIdx.x * 256 + threadIdx.x;
    if (t >= total) return;
    int r = t >> 4, c = t & 15;
    union { bf16x8 vec; unsigned short u[8]; } o;
    if (r < n) {
        float4 a = *(const float4*)(x + (size_t)r * 128 + c * 8);
        float4 b = *(const float4*)(x + (size_t)r * 128 + c * 8 + 4);
        o.u[0]=f2b(a.x); o.u[1]=f2b(a.y); o.u[2]=f2b(a.z); o.u[3]=f2b(a.w);
        o.u[4]=f2b(b.x); o.u[5]=f2b(b.y); o.u[6]=f2b(b.z); o.u[7]=f2b(b.w);
    } else {
        #pragma unroll
        for (int j = 0; j < 8; ++j) o.u[j] = 0;
    }
    *(bf16x8*)(xb + (size_t)r * 128 + c * 8) = o.vec;
}

// ---- convert 8 weight matrices [128k][128n] -> B-fragment order wf[mi][cb][t][lane][8] ----
__global__ __launch_bounds__(256) void convert_w_kernel(
    const float* __restrict__ W0, const float* __restrict__ W1,
    const float* __restrict__ W2, const float* __restrict__ W3,
    const float* __restrict__ W4, const float* __restrict__ W5,
    const float* __restrict__ W6, const float* __restrict__ W7,
    unsigned short* __restrict__ wf)
{
    int t = blockIdx.x * 256 + threadIdx.x;   // [mi][cb][tk][lane]
    if (t >= 16384) return;
    int mi = t >> 11, cb = (t >> 8) & 7, tk = (t >> 6) & 3, lane = t & 63;
    const float* W;
    switch (mi) {
        case 0: W = W0; break; case 1: W = W1; break;
        case 2: W = W2; break; case 3: W = W3; break;
        case 4: W = W4; break; case 5: W = W5; break;
        case 6: W = W6; break; default: W = W7; break;
    }
    int hi = lane >> 4, c = lane & 15;
    int col = cb * 16 + c;
    union { bf16x8 vec; unsigned short u[8]; } o;
    #pragma unroll
    for (int j = 0; j < 8; ++j) {
        int k = tk * 32 + hi * 8 + j;
        o.u[j] = f2b(W[k * 128 + col]);
    }
    *(bf16x8*)(wf + (size_t)t * 8) = o.vec;
}

// ---- MFMA projection from row-major bf16 xb; q/sp fp32, k/v interleaved bf16 ----
__global__ __launch_bounds__(256) void proj_mfma_kernel(
    const unsigned short* __restrict__ xb, const unsigned short* __restrict__ wf,
    const float* __restrict__ b0, const float* __restrict__ b1,
    const float* __restrict__ b2, const float* __restrict__ b3,
    float* __restrict__ qout, unsigned short* __restrict__ kvb,
    float* __restrict__ spout, int n)
{
    int mi = blockIdx.y;
    const float* bias;
    switch (mi) {
        case 0: bias = b0; break;
        case 1: bias = b1; break;
        case 2: bias = b2; break;
        default: bias = b3; break;
    }
    const bf16x8* wfv = (const bf16x8*)(wf + (size_t)mi * 16384);

    int wave = threadIdx.x >> 6, lane = threadIdx.x & 63;
    int rb0 = (blockIdx.x * 4 + wave) * 2;
    int rr = lane & 15, hi = lane >> 4;

    bf16x8 af[2][4];
    #pragma unroll
    for (int rb2 = 0; rb2 < 2; ++rb2) {
        int row = (rb0 + rb2) * 16 + rr;
        #pragma unroll
        for (int t = 0; t < 4; ++t)
            af[rb2][t] = *(const bf16x8*)(xb + (size_t)row * 128 + t * 32 + hi * 8);
    }

    int c = lane & 15, rowg = (lane >> 4) * 4;
    int r0 = rb0 * 16 + rowg;

    #pragma unroll
    for (int cb = 0; cb < 8; ++cb) {
        f32x4 acc0 = {0.f, 0.f, 0.f, 0.f};
        f32x4 acc1 = {0.f, 0.f, 0.f, 0.f};
        #pragma unroll
        for (int t = 0; t < 4; ++t) {
            bf16x8 bfr = wfv[(cb * 4 + t) * 64 + lane];
            acc0 = __builtin_amdgcn_mfma_f32_16x16x32_bf16(af[0][t], bfr, acc0, 0, 0, 0);
            acc1 = __builtin_amdgcn_mfma_f32_16x16x32_bf16(af[1][t], bfr, acc1, 0, 0, 0);
        }
        int col = cb * 16 + c;
        float bb = bias[col];
        #pragma unroll
        for (int reg = 0; reg < 4; ++reg) {
            #pragma unroll
            for (int half = 0; half < 2; ++half) {
                int ra = r0 + reg + half * 16;
                if (ra >= n) continue;
                float val = (half ? acc1[reg] : acc0[reg]) + bb;
                if (mi == 0)      qout[(size_t)ra * 128 + col] = val;
                else if (mi == 3) spout[(size_t)ra * 128 + col] = val;
                else if (mi == 1) kvb[(size_t)ra * 256 + col * 2]     = f2b(val);
                else              kvb[(size_t)ra * 256 + col * 2 + 1] = f2b(val);
            }
        }
    }
}

// ---- CSR build: degree histogram ----
__global__ __launch_bounds__(256) void deg_kernel(
    const int* __restrict__ dst, int* __restrict__ deg, int E)
{
    for (int e = blockIdx.x * blockDim.x + threadIdx.x; e < E;
         e += gridDim.x * blockDim.x)
        atomicAdd(&deg[dst[e]], 1);
}

// ---- device-wide 3-pass exclusive scan (coalesced, 1 elem/thread) ----
__global__ __launch_bounds__(256) void bsum_kernel(
    const int* __restrict__ deg, int* __restrict__ bsum, int n)
{
    int i = blockIdx.x * 256 + threadIdx.x;
    int v = (i < n) ? deg[i] : 0;
    #pragma unroll
    for (int o = 32; o; o >>= 1) v += __shfl_xor(v, o);
    __shared__ int ws[4];
    int wave = threadIdx.x >> 6, lane = threadIdx.x & 63;
    if (lane == 0) ws[wave] = v;
    __syncthreads();
    if (threadIdx.x == 0) bsum[blockIdx.x] = ws[0] + ws[1] + ws[2] + ws[3];
}

__global__ __launch_bounds__(1024) void bscan_kernel(
    const int* __restrict__ bsum, int* __restrict__ bexcl,
    int nb, int* __restrict__ off, int n)
{
    int t = threadIdx.x;
    int v = (t < nb) ? bsum[t] : 0;
    int orig = v;
    int lane = t & 63, wave = t >> 6;
    #pragma unroll
    for (int o = 1; o < 64; o <<= 1) {
        int up = __shfl_up(v, o);
        if (lane >= o) v += up;
    }
    __shared__ int ws[16];
    if (lane == 63) ws[wave] = v;
    __syncthreads();
    int pre = 0;
    for (int wv = 0; wv < wave; ++wv) pre += ws[wv];
    int incl = v + pre;
    if (t < nb) bexcl[t] = incl - orig;
    if (t == nb - 1) off[n] = incl;     // grand total
}

__global__ __launch_bounds__(256) void off_kernel(
    const int* __restrict__ deg, const int* __restrict__ bexcl,
    int* __restrict__ off, int* __restrict__ cursor, int n)
{
    int i = blockIdx.x * 256 + threadIdx.x;
    int v = (i < n) ? deg[i] : 0;
    int orig = v;
    int lane = threadIdx.x & 63, wave = threadIdx.x >> 6;
    #pragma unroll
    for (int o = 1; o < 64; o <<= 1) {
        int up = __shfl_up(v, o);
        if (lane >= o) v += up;
    }
    __shared__ int ws[4];
    if (lane == 63) ws[wave] = v;
    __syncthreads();
    int pre = bexcl[blockIdx.x];
    for (int wv = 0; wv < wave; ++wv) pre += ws[wv];
    if (i < n) {
        int ex = pre + v - orig;
        off[i] = ex;
        cursor[i] = ex;
    }
}

// ---- CSR build: fill src lists ----
__global__ __launch_bounds__(256) void fill_kernel(
    const int* __restrict__ src, const int* __restrict__ dst,
    int* __restrict__ cursor, int* __restrict__ csr_src, int E)
{
    for (int e = blockIdx.x * blockDim.x + threadIdx.x; e < E;
         e += gridDim.x * blockDim.x) {
        int d = dst[e];
        int p = atomicAdd(&cursor[d], 1);
        csr_src[p] = src[e];
    }
}

// ---- fused attention + online softmax + skip + LN; one wave/node ----
__global__ __launch_bounds__(256) void attn_ln_kernel(
    const float* __restrict__ q, const uint2* __restrict__ kvp,
    const float* __restrict__ sp,
    const int* __restrict__ off, const int* __restrict__ csr_src,
    const float* __restrict__ g, const float* __restrict__ b,
    float* __restrict__ outf, unsigned int* __restrict__ outb,
    int n, int relu)
{
    int node = blockIdx.x * 4 + (threadIdx.x >> 6);
    if (node >= n) return;
    int lane = threadIdx.x & 63;

    float2 qv = *(const float2*)(q + (size_t)node * 128 + lane * 2);
    int e0 = off[node], e1 = off[node + 1];

    float m = -INFINITY, ss = 0.f, a0 = 0.f, a1 = 0.f;

    int scur = (e0 < e1) ? csr_src[e0] : 0;
    uint2 kvc = make_uint2(0u, 0u);
    if (e0 < e1) kvc = kvp[(size_t)scur * 64 + lane];

    for (int i = e0; i < e1; ++i) {
        int sn = (i + 1 < e1) ? csr_src[i + 1] : scur;
        uint2 kvn = kvp[(size_t)sn * 64 + lane];

        float k0 = __uint_as_float(kvc.x << 16);
        float v0 = __uint_as_float(kvc.x & 0xFFFF0000u);
        float k1 = __uint_as_float(kvc.y << 16);
        float v1 = __uint_as_float(kvc.y & 0xFFFF0000u);

        float dot = qv.x * k0 + qv.y * k1;
        dot += __shfl_xor(dot, 1);
        dot += __shfl_xor(dot, 2);
        dot += __shfl_xor(dot, 4);
        dot += __shfl_xor(dot, 8);
        float al = dot * 0.17677669529663687f;   // 1/sqrt(32)

        float mn = fmaxf(m, al);
        float corr = __expf(m - mn);
        float w = __expf(al - mn);
        ss = ss * corr + w;
        a0 = a0 * corr + w * v0;
        a1 = a1 * corr + w * v1;
        m = mn;
        kvc = kvn;
    }

    float inv = (ss > 0.f) ? 1.f / ss : 0.f;
    float2 sv = *(const float2*)(sp + (size_t)node * 128 + lane * 2);
    float o0 = a0 * inv + sv.x;
    float o1 = a1 * inv + sv.y;

    float sum = o0 + o1;
    #pragma unroll
    for (int d = 32; d; d >>= 1) sum += __shfl_xor(sum, d);
    float mu = sum * (1.f / 128.f);
    float d0 = o0 - mu, d1 = o1 - mu;
    float vs = d0 * d0 + d1 * d1;
    #pragma unroll
    for (int d = 32; d; d >>= 1) vs += __shfl_xor(vs, d);
    float rstd = rsqrtf(vs * (1.f / 128.f) + LN_EPS);
    float r0 = d0 * rstd * g[lane * 2]     + b[lane * 2];
    float r1 = d1 * rstd * g[lane * 2 + 1] + b[lane * 2 + 1];
    if (relu) {
        r0 = fmaxf(r0, 0.f); r1 = fmaxf(r1, 0.f);
        outb[(size_t)node * 64 + lane] =
            (unsigned)f2b(r0) | ((unsigned)f2b(r1) << 16);
    } else {
        *(float2*)&outf[(size_t)node * 128 + lane * 2] = make_float2(r0, r1);
    }
}

extern "C" void kernel_launch(void* const* d_in, const int* in_sizes, int n_in,
                              void* d_out, int out_size, void* d_ws, size_t ws_size,
                              hipStream_t stream) {
    const float* x  = (const float*)d_in[0];
    const int*   ei = (const int*)d_in[1];
    const int n = in_sizes[0] / 128;
    const int E = in_sizes[1] / 2;
    const int* src = ei;
    const int* dst = ei + E;

    const float *Wq1 = (const float*)d_in[2],  *bq1 = (const float*)d_in[3];
    const float *Wk1 = (const float*)d_in[4],  *bk1 = (const float*)d_in[5];
    const float *Wv1 = (const float*)d_in[6],  *bv1 = (const float*)d_in[7];
    const float *Ws1 = (const float*)d_in[8],  *bs1 = (const float*)d_in[9];
    const float *g1  = (const float*)d_in[10], *be1 = (const float*)d_in[11];
    const float *Wq2 = (const float*)d_in[12], *bq2 = (const float*)d_in[13];
    const float *Wk2 = (const float*)d_in[14], *bk2 = (const float*)d_in[15];
    const float *Wv2 = (const float*)d_in[16], *bv2 = (const float*)d_in[17];
    const float *Ws2 = (const float*)d_in[18], *bs2 = (const float*)d_in[19];
    const float *g2  = (const float*)d_in[20], *be2 = (const float*)d_in[21];

    // geometry
    const int nrb    = (n + 15) / 16;
    const int nblk   = (nrb + 7) / 8;
    const int padrows = nblk * 8 * 16;
    const int nb     = (n + 255) / 256;          // scan blocks (<=1024 assumed)

    // workspace layout
    const size_t nf = (size_t)n * 128;
    char* w = (char*)d_ws;
    float* q  = (float*)w; w += nf * sizeof(float);
    float* sp = (float*)w; w += nf * sizeof(float);
    unsigned short* kvb = (unsigned short*)w; w += (size_t)n * 256 * sizeof(unsigned short);
    unsigned short* xb  = (unsigned short*)w; w += (size_t)padrows * 128 * sizeof(unsigned short);
    unsigned short* hb  = (unsigned short*)w; w += (size_t)padrows * 128 * sizeof(unsigned short);
    unsigned short* wf  = (unsigned short*)w; w += (size_t)8 * 16384 * sizeof(unsigned short);
    int* deg     = (int*)w; w += (size_t)(n + 1) * sizeof(int);
    int* off     = (int*)w; w += (size_t)(n + 1) * sizeof(int);
    int* cursor  = (int*)w; w += (size_t)(n + 1) * sizeof(int);
    int* bsum    = (int*)w; w += (size_t)nb * sizeof(int);
    int* bexcl   = (int*)w; w += (size_t)nb * sizeof(int);
    int* csr_src = (int*)w; w += (size_t)E * sizeof(int);

    dim3 projGrid(nblk, 4);
    int edgeBlocks = (E + 255) / 256; if (edgeBlocks > 2048) edgeBlocks = 2048;
    int nodeBlocks = (n + 3) / 4;
    int cvTotal  = padrows * 16;
    int cvBlocks = (cvTotal + 255) / 256;

    // ---------- one-time prep ----------
    convert_w_kernel<<<64, 256, 0, stream>>>(Wq1, Wk1, Wv1, Ws1, Wq2, Wk2, Wv2, Ws2, wf);
    hipMemsetAsync(deg, 0, (size_t)n * sizeof(int), stream);
    deg_kernel<<<edgeBlocks, 256, 0, stream>>>(dst, deg, E);
    bsum_kernel<<<nb, 256, 0, stream>>>(deg, bsum, n);
    bscan_kernel<<<1, 1024, 0, stream>>>(bsum, bexcl, nb, off, n);
    off_kernel<<<nb, 256, 0, stream>>>(deg, bexcl, off, cursor, n);
    fill_kernel<<<edgeBlocks, 256, 0, stream>>>(src, dst, cursor, csr_src, E);
    convert_xb_kernel<<<cvBlocks, 256, 0, stream>>>(x, xb, n, cvTotal);

    // ---------- layer 1 ----------
    proj_mfma_kernel<<<projGrid, 256, 0, stream>>>(xb, wf, bq1, bk1, bv1, bs1,
                                                   q, kvb, sp, n);
    attn_ln_kernel<<<nodeBlocks, 256, 0, stream>>>(q, (const uint2*)kvb, sp,
                                                   off, csr_src, g1, be1,
                                                   nullptr, (unsigned int*)hb, n, 1);

    // ---------- layer 2 ----------
    proj_mfma_kernel<<<projGrid, 256, 0, stream>>>(hb, wf + (size_t)4 * 16384,
                                                   bq2, bk2, bv2, bs2,
                                                   q, kvb, sp, n);
    attn_ln_kernel<<<nodeBlocks, 256, 0, stream>>>(q, (const uint2*)kvb, sp,
                                                   off, csr_src, g2, be2,
                                                   (float*)d_out, nullptr, n, 0);
}

// Round 6
// 338.251 us; speedup vs baseline: 10.2186x; 1.0507x over previous
//
#include <hip/hip_runtime.h>
#include <math.h>

#define LN_EPS 1e-5f
#define ATT_SCALE 0.17677669529663687f   // 1/sqrt(32)

typedef __attribute__((ext_vector_type(8))) short bf16x8;
typedef __attribute__((ext_vector_type(4))) float f32x4;

__device__ __forceinline__ unsigned short f2b(float f) {
    unsigned u = __float_as_uint(f);
    unsigned r = (u + 0x7FFFu + ((u >> 16) & 1)) >> 16;   // RNE
    return (unsigned short)r;
}
__device__ __forceinline__ float blo(unsigned w) { return __uint_as_float(w << 16); }
__device__ __forceinline__ float bhi(unsigned w) { return __uint_as_float(w & 0xFFFF0000u); }

// ---- convert fp32 [n][128] -> bf16 row-major [padrows][128], zero-padded ----
__global__ __launch_bounds__(256) void convert_xb_kernel(
    const float* __restrict__ x, unsigned short* __restrict__ xb,
    int n, int total)
{
    int t = blockIdx.x * 256 + threadIdx.x;
    if (t >= total) return;
    int r = t >> 4, c = t & 15;
    union { bf16x8 vec; unsigned short u[8]; } o;
    if (r < n) {
        float4 a = *(const float4*)(x + (size_t)r * 128 + c * 8);
        float4 b = *(const float4*)(x + (size_t)r * 128 + c * 8 + 4);
        o.u[0]=f2b(a.x); o.u[1]=f2b(a.y); o.u[2]=f2b(a.z); o.u[3]=f2b(a.w);
        o.u[4]=f2b(b.x); o.u[5]=f2b(b.y); o.u[6]=f2b(b.z); o.u[7]=f2b(b.w);
    } else {
        #pragma unroll
        for (int j = 0; j < 8; ++j) o.u[j] = 0;
    }
    *(bf16x8*)(xb + (size_t)r * 128 + c * 8) = o.vec;
}

// ---- convert 8 weight matrices -> B-fragment order wf[mi][cb][t][lane][8] ----
__global__ __launch_bounds__(256) void convert_w_kernel(
    const float* __restrict__ W0, const float* __restrict__ W1,
    const float* __restrict__ W2, const float* __restrict__ W3,
    const float* __restrict__ W4, const float* __restrict__ W5,
    const float* __restrict__ W6, const float* __restrict__ W7,
    unsigned short* __restrict__ wf)
{
    int t = blockIdx.x * 256 + threadIdx.x;
    if (t >= 16384) return;
    int mi = t >> 11, cb = (t >> 8) & 7, tk = (t >> 6) & 3, lane = t & 63;
    const float* W;
    switch (mi) {
        case 0: W = W0; break; case 1: W = W1; break;
        case 2: W = W2; break; case 3: W = W3; break;
        case 4: W = W4; break; case 5: W = W5; break;
        case 6: W = W6; break; default: W = W7; break;
    }
    int hi = lane >> 4, c = lane & 15;
    int col = cb * 16 + c;
    union { bf16x8 vec; unsigned short u[8]; } o;
    #pragma unroll
    for (int j = 0; j < 8; ++j) {
        int k = tk * 32 + hi * 8 + j;
        o.u[j] = f2b(W[k * 128 + col]);
    }
    *(bf16x8*)(wf + (size_t)t * 8) = o.vec;
}

// ---- fused 4-matrix MFMA projection; q bf16, k/v interleaved bf16, sp fp32 ----
__global__ __launch_bounds__(256) void proj_mfma_kernel(
    const unsigned short* __restrict__ xb, const unsigned short* __restrict__ wf,
    const float* __restrict__ b0, const float* __restrict__ b1,
    const float* __restrict__ b2, const float* __restrict__ b3,
    unsigned short* __restrict__ qb, unsigned short* __restrict__ kvb,
    float* __restrict__ spout, int n)
{
    const float* biases[4] = {b0, b1, b2, b3};
    int wave = threadIdx.x >> 6, lane = threadIdx.x & 63;
    int rb0 = (blockIdx.x * 4 + wave) * 2;
    int rr = lane & 15, hi = lane >> 4;

    bf16x8 af[2][4];
    #pragma unroll
    for (int rb2 = 0; rb2 < 2; ++rb2) {
        int row = (rb0 + rb2) * 16 + rr;
        #pragma unroll
        for (int t = 0; t < 4; ++t)
            af[rb2][t] = *(const bf16x8*)(xb + (size_t)row * 128 + t * 32 + hi * 8);
    }

    int c = lane & 15, rowg = (lane >> 4) * 4;
    int r0 = rb0 * 16 + rowg;

    #pragma unroll
    for (int mi = 0; mi < 4; ++mi) {
        const bf16x8* wfv = (const bf16x8*)(wf + (size_t)mi * 16384);
        const float* bias = biases[mi];
        #pragma unroll
        for (int cb = 0; cb < 8; ++cb) {
            f32x4 acc0 = {0.f, 0.f, 0.f, 0.f};
            f32x4 acc1 = {0.f, 0.f, 0.f, 0.f};
            #pragma unroll
            for (int t = 0; t < 4; ++t) {
                bf16x8 bfr = wfv[(cb * 4 + t) * 64 + lane];
                acc0 = __builtin_amdgcn_mfma_f32_16x16x32_bf16(af[0][t], bfr, acc0, 0, 0, 0);
                acc1 = __builtin_amdgcn_mfma_f32_16x16x32_bf16(af[1][t], bfr, acc1, 0, 0, 0);
            }
            int col = cb * 16 + c;
            float bb = bias[col];
            #pragma unroll
            for (int reg = 0; reg < 4; ++reg) {
                #pragma unroll
                for (int half = 0; half < 2; ++half) {
                    int ra = r0 + reg + half * 16;
                    if (ra >= n) continue;
                    float val = (half ? acc1[reg] : acc0[reg]) + bb;
                    if (mi == 0)      qb[(size_t)ra * 128 + col] = f2b(val);
                    else if (mi == 3) spout[(size_t)ra * 128 + col] = val;
                    else if (mi == 1) kvb[(size_t)ra * 256 + col * 2]     = f2b(val);
                    else              kvb[(size_t)ra * 256 + col * 2 + 1] = f2b(val);
                }
            }
        }
    }
}

// ---- CSR build: degree histogram ----
__global__ __launch_bounds__(256) void deg_kernel(
    const int* __restrict__ dst, int* __restrict__ deg, int E)
{
    for (int e = blockIdx.x * blockDim.x + threadIdx.x; e < E;
         e += gridDim.x * blockDim.x)
        atomicAdd(&deg[dst[e]], 1);
}

// ---- device-wide 3-pass exclusive scan ----
__global__ __launch_bounds__(256) void bsum_kernel(
    const int* __restrict__ deg, int* __restrict__ bsum, int n)
{
    int i = blockIdx.x * 256 + threadIdx.x;
    int v = (i < n) ? deg[i] : 0;
    #pragma unroll
    for (int o = 32; o; o >>= 1) v += __shfl_xor(v, o);
    __shared__ int ws[4];
    int wave = threadIdx.x >> 6, lane = threadIdx.x & 63;
    if (lane == 0) ws[wave] = v;
    __syncthreads();
    if (threadIdx.x == 0) bsum[blockIdx.x] = ws[0] + ws[1] + ws[2] + ws[3];
}

__global__ __launch_bounds__(1024) void bscan_kernel(
    const int* __restrict__ bsum, int* __restrict__ bexcl,
    int nb, int* __restrict__ off, int n)
{
    int t = threadIdx.x;
    int v = (t < nb) ? bsum[t] : 0;
    int orig = v;
    int lane = t & 63, wave = t >> 6;
    #pragma unroll
    for (int o = 1; o < 64; o <<= 1) {
        int up = __shfl_up(v, o);
        if (lane >= o) v += up;
    }
    __shared__ int ws[16];
    if (lane == 63) ws[wave] = v;
    __syncthreads();
    int pre = 0;
    for (int wv = 0; wv < wave; ++wv) pre += ws[wv];
    int incl = v + pre;
    if (t < nb) bexcl[t] = incl - orig;
    if (t == nb - 1) off[n] = incl;
}

__global__ __launch_bounds__(256) void off_kernel(
    const int* __restrict__ deg, const int* __restrict__ bexcl,
    int* __restrict__ off, int* __restrict__ cursor, int n)
{
    int i = blockIdx.x * 256 + threadIdx.x;
    int v = (i < n) ? deg[i] : 0;
    int orig = v;
    int lane = threadIdx.x & 63, wave = threadIdx.x >> 6;
    #pragma unroll
    for (int o = 1; o < 64; o <<= 1) {
        int up = __shfl_up(v, o);
        if (lane >= o) v += up;
    }
    __shared__ int ws[4];
    if (lane == 63) ws[wave] = v;
    __syncthreads();
    int pre = bexcl[blockIdx.x];
    for (int wv = 0; wv < wave; ++wv) pre += ws[wv];
    if (i < n) {
        int ex = pre + v - orig;
        off[i] = ex;
        cursor[i] = ex;
    }
}

__global__ __launch_bounds__(256) void fill_kernel(
    const int* __restrict__ src, const int* __restrict__ dst,
    int* __restrict__ cursor, int* __restrict__ csr_src, int E)
{
    for (int e = blockIdx.x * blockDim.x + threadIdx.x; e < E;
         e += gridDim.x * blockDim.x) {
        int d = dst[e];
        int p = atomicAdd(&cursor[d], 1);
        csr_src[p] = src[e];
    }
}

// ---- fused attention + online softmax + skip + LN; one wave/node ----
// 2-edge unroll, 1 exp/edge, 2-deep kv prefetch.
__global__ __launch_bounds__(256) void attn_ln_kernel(
    const unsigned int* __restrict__ qb, const uint2* __restrict__ kvp,
    const float* __restrict__ sp,
    const int* __restrict__ off, const int* __restrict__ csr_src,
    const float* __restrict__ g, const float* __restrict__ b,
    float* __restrict__ outf, unsigned int* __restrict__ outb,
    int n, int relu)
{
    int node = blockIdx.x * 4 + (threadIdx.x >> 6);
    if (node >= n) return;
    int lane = threadIdx.x & 63;

    unsigned qw = qb[(size_t)node * 64 + lane];
    float qx = blo(qw), qy = bhi(qw);

    int e0 = off[node], e1 = off[node + 1];
    int cnt = e1 - e0;

    float m = -INFINITY, ss = 0.f, a0 = 0.f, a1 = 0.f;

    uint2 kvA = make_uint2(0u, 0u), kvB = kvA;
    if (cnt > 0) { int s = csr_src[e0];     kvA = kvp[(size_t)s * 64 + lane]; }
    if (cnt > 1) { int s = csr_src[e0 + 1]; kvB = kvp[(size_t)s * 64 + lane]; }

    int i = e0;
    for (; i + 1 < e1; i += 2) {
        int sC = (i + 2 < e1) ? csr_src[i + 2] : 0;
        int sD = (i + 3 < e1) ? csr_src[i + 3] : 0;
        uint2 kvC = kvp[(size_t)sC * 64 + lane];
        uint2 kvD = kvp[(size_t)sD * 64 + lane];

        float kA0 = blo(kvA.x), vA0 = bhi(kvA.x), kA1 = blo(kvA.y), vA1 = bhi(kvA.y);
        float kB0 = blo(kvB.x), vB0 = bhi(kvB.x), kB1 = blo(kvB.y), vB1 = bhi(kvB.y);

        float dA = qx * kA0 + qy * kA1;
        float dB = qx * kB0 + qy * kB1;
        dA += __shfl_xor(dA, 1); dB += __shfl_xor(dB, 1);
        dA += __shfl_xor(dA, 2); dB += __shfl_xor(dB, 2);
        dA += __shfl_xor(dA, 4); dB += __shfl_xor(dB, 4);
        dA += __shfl_xor(dA, 8); dB += __shfl_xor(dB, 8);
        float alA = dA * ATT_SCALE, alB = dB * ATT_SCALE;

        // pair-local softmax: one exp
        float dpair = alA - alB;
        float ep = __expf(-fabsf(dpair));
        float wA = (dpair < 0.f) ? ep : 1.f;
        float wB = (dpair < 0.f) ? 1.f : ep;
        float mp = fmaxf(alA, alB);
        // merge into running state: one exp
        float dm = mp - m;
        float em = __expf(-fabsf(dm));
        float corr = (dm > 0.f) ? em : 1.f;
        float wp   = (dm > 0.f) ? 1.f : em;
        m = fmaxf(m, mp);
        ss = ss * corr + wp * (wA + wB);
        a0 = a0 * corr + wp * (wA * vA0 + wB * vB0);
        a1 = a1 * corr + wp * (wA * vA1 + wB * vB1);

        kvA = kvC; kvB = kvD;
    }
    if (cnt & 1) {   // last unpaired edge sits in kvA
        float kA0 = blo(kvA.x), vA0 = bhi(kvA.x), kA1 = blo(kvA.y), vA1 = bhi(kvA.y);
        float dA = qx * kA0 + qy * kA1;
        dA += __shfl_xor(dA, 1);
        dA += __shfl_xor(dA, 2);
        dA += __shfl_xor(dA, 4);
        dA += __shfl_xor(dA, 8);
        float al = dA * ATT_SCALE;
        float dm = al - m;
        float em = __expf(-fabsf(dm));
        float corr = (dm > 0.f) ? em : 1.f;
        float w    = (dm > 0.f) ? 1.f : em;
        m = fmaxf(m, al);
        ss = ss * corr + w;
        a0 = a0 * corr + w * vA0;
        a1 = a1 * corr + w * vA1;
    }

    float inv = (ss > 0.f) ? 1.f / ss : 0.f;
    float2 sv = *(const float2*)(sp + (size_t)node * 128 + lane * 2);
    float o0 = a0 * inv + sv.x;
    float o1 = a1 * inv + sv.y;

    float sum = o0 + o1;
    #pragma unroll
    for (int d = 32; d; d >>= 1) sum += __shfl_xor(sum, d);
    float mu = sum * (1.f / 128.f);
    float d0 = o0 - mu, d1 = o1 - mu;
    float vs = d0 * d0 + d1 * d1;
    #pragma unroll
    for (int d = 32; d; d >>= 1) vs += __shfl_xor(vs, d);
    float rstd = rsqrtf(vs * (1.f / 128.f) + LN_EPS);
    float r0 = d0 * rstd * g[lane * 2]     + b[lane * 2];
    float r1 = d1 * rstd * g[lane * 2 + 1] + b[lane * 2 + 1];
    if (relu) {
        r0 = fmaxf(r0, 0.f); r1 = fmaxf(r1, 0.f);
        outb[(size_t)node * 64 + lane] =
            (unsigned)f2b(r0) | ((unsigned)f2b(r1) << 16);
    } else {
        *(float2*)&outf[(size_t)node * 128 + lane * 2] = make_float2(r0, r1);
    }
}

extern "C" void kernel_launch(void* const* d_in, const int* in_sizes, int n_in,
                              void* d_out, int out_size, void* d_ws, size_t ws_size,
                              hipStream_t stream) {
    const float* x  = (const float*)d_in[0];
    const int*   ei = (const int*)d_in[1];
    const int n = in_sizes[0] / 128;
    const int E = in_sizes[1] / 2;
    const int* src = ei;
    const int* dst = ei + E;

    const float *Wq1 = (const float*)d_in[2],  *bq1 = (const float*)d_in[3];
    const float *Wk1 = (const float*)d_in[4],  *bk1 = (const float*)d_in[5];
    const float *Wv1 = (const float*)d_in[6],  *bv1 = (const float*)d_in[7];
    const float *Ws1 = (const float*)d_in[8],  *bs1 = (const float*)d_in[9];
    const float *g1  = (const float*)d_in[10], *be1 = (const float*)d_in[11];
    const float *Wq2 = (const float*)d_in[12], *bq2 = (const float*)d_in[13];
    const float *Wk2 = (const float*)d_in[14], *bk2 = (const float*)d_in[15];
    const float *Wv2 = (const float*)d_in[16], *bv2 = (const float*)d_in[17];
    const float *Ws2 = (const float*)d_in[18], *bs2 = (const float*)d_in[19];
    const float *g2  = (const float*)d_in[20], *be2 = (const float*)d_in[21];

    // geometry
    const int nrb     = (n + 15) / 16;
    const int nblk    = (nrb + 7) / 8;
    const int padrows = nblk * 8 * 16;
    const int nb      = (n + 255) / 256;

    // workspace layout
    const size_t nf = (size_t)n * 128;
    char* w = (char*)d_ws;
    float* sp = (float*)w; w += nf * sizeof(float);
    unsigned short* qb  = (unsigned short*)w; w += nf * sizeof(unsigned short);
    unsigned short* kvb = (unsigned short*)w; w += (size_t)n * 256 * sizeof(unsigned short);
    unsigned short* xb  = (unsigned short*)w; w += (size_t)padrows * 128 * sizeof(unsigned short);
    unsigned short* hb  = (unsigned short*)w; w += (size_t)padrows * 128 * sizeof(unsigned short);
    unsigned short* wf  = (unsigned short*)w; w += (size_t)8 * 16384 * sizeof(unsigned short);
    int* deg     = (int*)w; w += (size_t)(n + 1) * sizeof(int);
    int* off     = (int*)w; w += (size_t)(n + 1) * sizeof(int);
    int* cursor  = (int*)w; w += (size_t)(n + 1) * sizeof(int);
    int* bsum    = (int*)w; w += (size_t)nb * sizeof(int);
    int* bexcl   = (int*)w; w += (size_t)nb * sizeof(int);
    int* csr_src = (int*)w; w += (size_t)E * sizeof(int);

    int edgeBlocks = (E + 255) / 256; if (edgeBlocks > 2048) edgeBlocks = 2048;
    int nodeBlocks = (n + 3) / 4;
    int cvTotal  = padrows * 16;
    int cvBlocks = (cvTotal + 255) / 256;

    // ---------- one-time prep ----------
    convert_w_kernel<<<64, 256, 0, stream>>>(Wq1, Wk1, Wv1, Ws1, Wq2, Wk2, Wv2, Ws2, wf);
    hipMemsetAsync(deg, 0, (size_t)n * sizeof(int), stream);
    deg_kernel<<<edgeBlocks, 256, 0, stream>>>(dst, deg, E);
    bsum_kernel<<<nb, 256, 0, stream>>>(deg, bsum, n);
    bscan_kernel<<<1, 1024, 0, stream>>>(bsum, bexcl, nb, off, n);
    off_kernel<<<nb, 256, 0, stream>>>(deg, bexcl, off, cursor, n);
    fill_kernel<<<edgeBlocks, 256, 0, stream>>>(src, dst, cursor, csr_src, E);
    convert_xb_kernel<<<cvBlocks, 256, 0, stream>>>(x, xb, n, cvTotal);

    // ---------- layer 1 ----------
    proj_mfma_kernel<<<nblk, 256, 0, stream>>>(xb, wf, bq1, bk1, bv1, bs1,
                                               qb, kvb, sp, n);
    attn_ln_kernel<<<nodeBlocks, 256, 0, stream>>>((const unsigned int*)qb,
                                                   (const uint2*)kvb, sp,
                                                   off, csr_src, g1, be1,
                                                   nullptr, (unsigned int*)hb, n, 1);

    // ---------- layer 2 ----------
    proj_mfma_kernel<<<nblk, 256, 0, stream>>>(hb, wf + (size_t)4 * 16384,
                                               bq2, bk2, bv2, bs2,
                                               qb, kvb, sp, n);
    attn_ln_kernel<<<nodeBlocks, 256, 0, stream>>>((const unsigned int*)qb,
                                                   (const uint2*)kvb, sp,
                                                   off, csr_src, g2, be2,
                                                   (float*)d_out, nullptr, n, 0);
}

// Round 7
// 300.887 us; speedup vs baseline: 11.4876x; 1.1242x over previous
//
#include <hip/hip_runtime.h>
#include <math.h>

#define LN_EPS 1e-5f
#define ATT_SCALE 0.17677669529663687f   // 1/sqrt(32)

typedef __attribute__((ext_vector_type(8))) short bf16x8;
typedef __attribute__((ext_vector_type(4))) float f32x4;

__device__ __forceinline__ unsigned short f2b(float f) {
    unsigned u = __float_as_uint(f);
    unsigned r = (u + 0x7FFFu + ((u >> 16) & 1)) >> 16;   // RNE
    return (unsigned short)r;
}
__device__ __forceinline__ float blo(unsigned w) { return __uint_as_float(w << 16); }
__device__ __forceinline__ float bhi(unsigned w) { return __uint_as_float(w & 0xFFFF0000u); }

// ---- convert fp32 [n][128] -> bf16 row-major [padrows][128], zero-padded ----
__global__ __launch_bounds__(256) void convert_xb_kernel(
    const float* __restrict__ x, unsigned short* __restrict__ xb,
    int n, int total)
{
    int t = blockIdx.x * 256 + threadIdx.x;
    if (t >= total) return;
    int r = t >> 4, c = t & 15;
    union { bf16x8 vec; unsigned short u[8]; } o;
    if (r < n) {
        float4 a = *(const float4*)(x + (size_t)r * 128 + c * 8);
        float4 b = *(const float4*)(x + (size_t)r * 128 + c * 8 + 4);
        o.u[0]=f2b(a.x); o.u[1]=f2b(a.y); o.u[2]=f2b(a.z); o.u[3]=f2b(a.w);
        o.u[4]=f2b(b.x); o.u[5]=f2b(b.y); o.u[6]=f2b(b.z); o.u[7]=f2b(b.w);
    } else {
        #pragma unroll
        for (int j = 0; j < 8; ++j) o.u[j] = 0;
    }
    *(bf16x8*)(xb + (size_t)r * 128 + c * 8) = o.vec;
}

// ---- convert 8 weight matrices -> B-fragment order wf[mi][cb][t][lane][8] ----
__global__ __launch_bounds__(256) void convert_w_kernel(
    const float* __restrict__ W0, const float* __restrict__ W1,
    const float* __restrict__ W2, const float* __restrict__ W3,
    const float* __restrict__ W4, const float* __restrict__ W5,
    const float* __restrict__ W6, const float* __restrict__ W7,
    unsigned short* __restrict__ wf)
{
    int t = blockIdx.x * 256 + threadIdx.x;
    if (t >= 16384) return;
    int mi = t >> 11, cb = (t >> 8) & 7, tk = (t >> 6) & 3, lane = t & 63;
    const float* W;
    switch (mi) {
        case 0: W = W0; break; case 1: W = W1; break;
        case 2: W = W2; break; case 3: W = W3; break;
        case 4: W = W4; break; case 5: W = W5; break;
        case 6: W = W6; break; default: W = W7; break;
    }
    int hi = lane >> 4, c = lane & 15;
    int col = cb * 16 + c;
    union { bf16x8 vec; unsigned short u[8]; } o;
    #pragma unroll
    for (int j = 0; j < 8; ++j) {
        int k = tk * 32 + hi * 8 + j;
        o.u[j] = f2b(W[k * 128 + col]);
    }
    *(bf16x8*)(wf + (size_t)t * 8) = o.vec;
}

// ---- fused 4-matrix MFMA projection; q bf16, k/v interleaved bf16, sp fp32 ----
__global__ __launch_bounds__(256) void proj_mfma_kernel(
    const unsigned short* __restrict__ xb, const unsigned short* __restrict__ wf,
    const float* __restrict__ b0, const float* __restrict__ b1,
    const float* __restrict__ b2, const float* __restrict__ b3,
    unsigned short* __restrict__ qb, unsigned short* __restrict__ kvb,
    float* __restrict__ spout, int n)
{
    const float* biases[4] = {b0, b1, b2, b3};
    int wave = threadIdx.x >> 6, lane = threadIdx.x & 63;
    int rb0 = (blockIdx.x * 4 + wave) * 2;
    int rr = lane & 15, hi = lane >> 4;

    bf16x8 af[2][4];
    #pragma unroll
    for (int rb2 = 0; rb2 < 2; ++rb2) {
        int row = (rb0 + rb2) * 16 + rr;
        #pragma unroll
        for (int t = 0; t < 4; ++t)
            af[rb2][t] = *(const bf16x8*)(xb + (size_t)row * 128 + t * 32 + hi * 8);
    }

    int c = lane & 15, rowg = (lane >> 4) * 4;
    int r0 = rb0 * 16 + rowg;

    #pragma unroll
    for (int mi = 0; mi < 4; ++mi) {
        const bf16x8* wfv = (const bf16x8*)(wf + (size_t)mi * 16384);
        const float* bias = biases[mi];
        #pragma unroll
        for (int cb = 0; cb < 8; ++cb) {
            f32x4 acc0 = {0.f, 0.f, 0.f, 0.f};
            f32x4 acc1 = {0.f, 0.f, 0.f, 0.f};
            #pragma unroll
            for (int t = 0; t < 4; ++t) {
                bf16x8 bfr = wfv[(cb * 4 + t) * 64 + lane];
                acc0 = __builtin_amdgcn_mfma_f32_16x16x32_bf16(af[0][t], bfr, acc0, 0, 0, 0);
                acc1 = __builtin_amdgcn_mfma_f32_16x16x32_bf16(af[1][t], bfr, acc1, 0, 0, 0);
            }
            int col = cb * 16 + c;
            float bb = bias[col];
            #pragma unroll
            for (int reg = 0; reg < 4; ++reg) {
                #pragma unroll
                for (int half = 0; half < 2; ++half) {
                    int ra = r0 + reg + half * 16;
                    if (ra >= n) continue;
                    float val = (half ? acc1[reg] : acc0[reg]) + bb;
                    if (mi == 0)      qb[(size_t)ra * 128 + col] = f2b(val);
                    else if (mi == 3) spout[(size_t)ra * 128 + col] = val;
                    else if (mi == 1) kvb[(size_t)ra * 256 + col * 2]     = f2b(val);
                    else              kvb[(size_t)ra * 256 + col * 2 + 1] = f2b(val);
                }
            }
        }
    }
}

// ---- CSR build: degree histogram ----
__global__ __launch_bounds__(256) void deg_kernel(
    const int* __restrict__ dst, int* __restrict__ deg, int E)
{
    for (int e = blockIdx.x * blockDim.x + threadIdx.x; e < E;
         e += gridDim.x * blockDim.x)
        atomicAdd(&deg[dst[e]], 1);
}

// ---- device-wide 3-pass exclusive scan ----
__global__ __launch_bounds__(256) void bsum_kernel(
    const int* __restrict__ deg, int* __restrict__ bsum, int n)
{
    int i = blockIdx.x * 256 + threadIdx.x;
    int v = (i < n) ? deg[i] : 0;
    #pragma unroll
    for (int o = 32; o; o >>= 1) v += __shfl_xor(v, o);
    __shared__ int ws[4];
    int wave = threadIdx.x >> 6, lane = threadIdx.x & 63;
    if (lane == 0) ws[wave] = v;
    __syncthreads();
    if (threadIdx.x == 0) bsum[blockIdx.x] = ws[0] + ws[1] + ws[2] + ws[3];
}

__global__ __launch_bounds__(1024) void bscan_kernel(
    const int* __restrict__ bsum, int* __restrict__ bexcl,
    int nb, int* __restrict__ off, int n)
{
    int t = threadIdx.x;
    int v = (t < nb) ? bsum[t] : 0;
    int orig = v;
    int lane = t & 63, wave = t >> 6;
    #pragma unroll
    for (int o = 1; o < 64; o <<= 1) {
        int up = __shfl_up(v, o);
        if (lane >= o) v += up;
    }
    __shared__ int ws[16];
    if (lane == 63) ws[wave] = v;
    __syncthreads();
    int pre = 0;
    for (int wv = 0; wv < wave; ++wv) pre += ws[wv];
    int incl = v + pre;
    if (t < nb) bexcl[t] = incl - orig;
    if (t == nb - 1) off[n] = incl;
}

__global__ __launch_bounds__(256) void off_kernel(
    const int* __restrict__ deg, const int* __restrict__ bexcl,
    int* __restrict__ off, int* __restrict__ cursor, int n)
{
    int i = blockIdx.x * 256 + threadIdx.x;
    int v = (i < n) ? deg[i] : 0;
    int orig = v;
    int lane = threadIdx.x & 63, wave = threadIdx.x >> 6;
    #pragma unroll
    for (int o = 1; o < 64; o <<= 1) {
        int up = __shfl_up(v, o);
        if (lane >= o) v += up;
    }
    __shared__ int ws[4];
    if (lane == 63) ws[wave] = v;
    __syncthreads();
    int pre = bexcl[blockIdx.x];
    for (int wv = 0; wv < wave; ++wv) pre += ws[wv];
    if (i < n) {
        int ex = pre + v - orig;
        off[i] = ex;
        cursor[i] = ex;
    }
}

__global__ __launch_bounds__(256) void fill_kernel(
    const int* __restrict__ src, const int* __restrict__ dst,
    int* __restrict__ cursor, int* __restrict__ csr_src, int E)
{
    for (int e = blockIdx.x * blockDim.x + threadIdx.x; e < E;
         e += gridDim.x * blockDim.x) {
        int d = dst[e];
        int p = atomicAdd(&cursor[d], 1);
        csr_src[p] = src[e];
    }
}

// ---- fused attention + online softmax + skip + LN; one wave/node ----
// 4 slots x 16 lanes: 4 edges in flight, lane owns 8 dims (head = 4 lanes).
__global__ __launch_bounds__(256) void attn_ln_kernel(
    const uint4* __restrict__ qb4,     // [n][16] uint4 = 128 bf16/row
    const uint4* __restrict__ kv4,     // [n][32] uint4 = 512 B/row
    const float4* __restrict__ sp4,    // [n][32] float4
    const int* __restrict__ off, const int* __restrict__ csr_src,
    const float4* __restrict__ g4, const float4* __restrict__ b4,
    float4* __restrict__ outf, uint4* __restrict__ outb,
    int n, int relu)
{
    int node = blockIdx.x * 4 + (threadIdx.x >> 6);
    if (node >= n) return;
    int lane = threadIdx.x & 63;
    int slot = lane >> 4, ll = lane & 15;

    // q: 8 dims for this lane (replicated across slots)
    uint4 qw = qb4[(size_t)node * 16 + ll];
    float qf[8];
    qf[0]=blo(qw.x); qf[1]=bhi(qw.x); qf[2]=blo(qw.y); qf[3]=bhi(qw.y);
    qf[4]=blo(qw.z); qf[5]=bhi(qw.z); qf[6]=blo(qw.w); qf[7]=bhi(qw.w);

    int e0 = off[node], e1 = off[node + 1];
    int cnt = e1 - e0;
    int T = (cnt + 3) >> 2;

    float m = -1e30f, ss = 0.f;
    float a[8];
    #pragma unroll
    for (int j = 0; j < 8; ++j) a[j] = 0.f;

    // prefetch first edge of this slot
    int idx = e0 + slot;
    int vA = (idx < e1);
    int sA = vA ? csr_src[idx] : 0;
    uint4 cA0 = kv4[(size_t)sA * 32 + 2 * ll];
    uint4 cA1 = kv4[(size_t)sA * 32 + 2 * ll + 1];

    for (int t = 0; t < T; ++t) {
        int nidx = idx + 4;
        int vN = (nidx < e1);
        int sN = vN ? csr_src[nidx] : 0;
        uint4 cN0 = kv4[(size_t)sN * 32 + 2 * ll];
        uint4 cN1 = kv4[(size_t)sN * 32 + 2 * ll + 1];

        float kf[8], vf[8];
        kf[0]=blo(cA0.x); vf[0]=bhi(cA0.x); kf[1]=blo(cA0.y); vf[1]=bhi(cA0.y);
        kf[2]=blo(cA0.z); vf[2]=bhi(cA0.z); kf[3]=blo(cA0.w); vf[3]=bhi(cA0.w);
        kf[4]=blo(cA1.x); vf[4]=bhi(cA1.x); kf[5]=blo(cA1.y); vf[5]=bhi(cA1.y);
        kf[6]=blo(cA1.z); vf[6]=bhi(cA1.z); kf[7]=blo(cA1.w); vf[7]=bhi(cA1.w);

        float dot = qf[0]*kf[0];
        #pragma unroll
        for (int j = 1; j < 8; ++j) dot = fmaf(qf[j], kf[j], dot);
        dot += __shfl_xor(dot, 1);     // reduce over the head's 4 lanes
        dot += __shfl_xor(dot, 2);

        float al = vA ? dot * ATT_SCALE : -1e38f;
        float dm = al - m;
        float em = __expf(-fabsf(dm));
        float corr = (dm > 0.f) ? em : 1.f;
        float w    = (dm > 0.f) ? 1.f : em;
        m = fmaxf(m, al);
        ss = ss * corr + w;
        #pragma unroll
        for (int j = 0; j < 8; ++j) a[j] = fmaf(w, vf[j], a[j] * corr);

        idx = nidx; vA = vN; cA0 = cN0; cA1 = cN1;
    }

    // combine the 4 slots' online-softmax states (flash merge)
    float mg = m;
    mg = fmaxf(mg, __shfl_xor(mg, 16));
    mg = fmaxf(mg, __shfl_xor(mg, 32));
    float sc = __expf(m - mg);          // 0 for empty slots (m=-1e30)
    float ssg = ss * sc;
    ssg += __shfl_xor(ssg, 16);
    ssg += __shfl_xor(ssg, 32);
    #pragma unroll
    for (int j = 0; j < 8; ++j) {
        float aj = a[j] * sc;
        aj += __shfl_xor(aj, 16);
        aj += __shfl_xor(aj, 32);
        a[j] = aj;
    }

    float inv = (ssg > 0.f) ? 1.f / ssg : 0.f;
    float4 s0 = sp4[(size_t)node * 32 + 2 * ll];
    float4 s1 = sp4[(size_t)node * 32 + 2 * ll + 1];
    float o[8];
    o[0]=fmaf(a[0],inv,s0.x); o[1]=fmaf(a[1],inv,s0.y);
    o[2]=fmaf(a[2],inv,s0.z); o[3]=fmaf(a[3],inv,s0.w);
    o[4]=fmaf(a[4],inv,s1.x); o[5]=fmaf(a[5],inv,s1.y);
    o[6]=fmaf(a[6],inv,s1.z); o[7]=fmaf(a[7],inv,s1.w);

    // layernorm over 128 dims = 16 lanes x 8 (replicated across slots)
    float sum = o[0]+o[1]+o[2]+o[3]+o[4]+o[5]+o[6]+o[7];
    sum += __shfl_xor(sum, 1); sum += __shfl_xor(sum, 2);
    sum += __shfl_xor(sum, 4); sum += __shfl_xor(sum, 8);
    float mu = sum * (1.f / 128.f);
    float var = 0.f;
    float d[8];
    #pragma unroll
    for (int j = 0; j < 8; ++j) { d[j] = o[j] - mu; var = fmaf(d[j], d[j], var); }
    var += __shfl_xor(var, 1); var += __shfl_xor(var, 2);
    var += __shfl_xor(var, 4); var += __shfl_xor(var, 8);
    float rstd = rsqrtf(var * (1.f / 128.f) + LN_EPS);

    float4 gg0 = g4[2 * ll], gg1 = g4[2 * ll + 1];
    float4 bb0 = b4[2 * ll], bb1 = b4[2 * ll + 1];
    float r[8];
    r[0]=fmaf(d[0]*rstd, gg0.x, bb0.x); r[1]=fmaf(d[1]*rstd, gg0.y, bb0.y);
    r[2]=fmaf(d[2]*rstd, gg0.z, bb0.z); r[3]=fmaf(d[3]*rstd, gg0.w, bb0.w);
    r[4]=fmaf(d[4]*rstd, gg1.x, bb1.x); r[5]=fmaf(d[5]*rstd, gg1.y, bb1.y);
    r[6]=fmaf(d[6]*rstd, gg1.z, bb1.z); r[7]=fmaf(d[7]*rstd, gg1.w, bb1.w);

    if (slot == 0) {
        if (relu) {
            #pragma unroll
            for (int j = 0; j < 8; ++j) r[j] = fmaxf(r[j], 0.f);
            uint4 ow;
            ow.x = (unsigned)f2b(r[0]) | ((unsigned)f2b(r[1]) << 16);
            ow.y = (unsigned)f2b(r[2]) | ((unsigned)f2b(r[3]) << 16);
            ow.z = (unsigned)f2b(r[4]) | ((unsigned)f2b(r[5]) << 16);
            ow.w = (unsigned)f2b(r[6]) | ((unsigned)f2b(r[7]) << 16);
            outb[(size_t)node * 16 + ll] = ow;
        } else {
            outf[(size_t)node * 32 + 2 * ll]     = make_float4(r[0], r[1], r[2], r[3]);
            outf[(size_t)node * 32 + 2 * ll + 1] = make_float4(r[4], r[5], r[6], r[7]);
        }
    }
}

extern "C" void kernel_launch(void* const* d_in, const int* in_sizes, int n_in,
                              void* d_out, int out_size, void* d_ws, size_t ws_size,
                              hipStream_t stream) {
    const float* x  = (const float*)d_in[0];
    const int*   ei = (const int*)d_in[1];
    const int n = in_sizes[0] / 128;
    const int E = in_sizes[1] / 2;
    const int* src = ei;
    const int* dst = ei + E;

    const float *Wq1 = (const float*)d_in[2],  *bq1 = (const float*)d_in[3];
    const float *Wk1 = (const float*)d_in[4],  *bk1 = (const float*)d_in[5];
    const float *Wv1 = (const float*)d_in[6],  *bv1 = (const float*)d_in[7];
    const float *Ws1 = (const float*)d_in[8],  *bs1 = (const float*)d_in[9];
    const float *g1  = (const float*)d_in[10], *be1 = (const float*)d_in[11];
    const float *Wq2 = (const float*)d_in[12], *bq2 = (const float*)d_in[13];
    const float *Wk2 = (const float*)d_in[14], *bk2 = (const float*)d_in[15];
    const float *Wv2 = (const float*)d_in[16], *bv2 = (const float*)d_in[17];
    const float *Ws2 = (const float*)d_in[18], *bs2 = (const float*)d_in[19];
    const float *g2  = (const float*)d_in[20], *be2 = (const float*)d_in[21];

    // geometry
    const int nrb     = (n + 15) / 16;
    const int nblk    = (nrb + 7) / 8;
    const int padrows = nblk * 8 * 16;
    const int nb      = (n + 255) / 256;

    // workspace layout
    const size_t nf = (size_t)n * 128;
    char* w = (char*)d_ws;
    float* sp = (float*)w; w += nf * sizeof(float);
    unsigned short* qb  = (unsigned short*)w; w += nf * sizeof(unsigned short);
    unsigned short* kvb = (unsigned short*)w; w += (size_t)n * 256 * sizeof(unsigned short);
    unsigned short* xb  = (unsigned short*)w; w += (size_t)padrows * 128 * sizeof(unsigned short);
    unsigned short* hb  = (unsigned short*)w; w += (size_t)padrows * 128 * sizeof(unsigned short);
    unsigned short* wf  = (unsigned short*)w; w += (size_t)8 * 16384 * sizeof(unsigned short);
    int* deg     = (int*)w; w += (size_t)(n + 1) * sizeof(int);
    int* off     = (int*)w; w += (size_t)(n + 1) * sizeof(int);
    int* cursor  = (int*)w; w += (size_t)(n + 1) * sizeof(int);
    int* bsum    = (int*)w; w += (size_t)nb * sizeof(int);
    int* bexcl   = (int*)w; w += (size_t)nb * sizeof(int);
    int* csr_src = (int*)w; w += (size_t)E * sizeof(int);

    int edgeBlocks = (E + 255) / 256; if (edgeBlocks > 2048) edgeBlocks = 2048;
    int nodeBlocks = (n + 3) / 4;
    int cvTotal  = padrows * 16;
    int cvBlocks = (cvTotal + 255) / 256;

    // ---------- one-time prep ----------
    convert_w_kernel<<<64, 256, 0, stream>>>(Wq1, Wk1, Wv1, Ws1, Wq2, Wk2, Wv2, Ws2, wf);
    hipMemsetAsync(deg, 0, (size_t)n * sizeof(int), stream);
    deg_kernel<<<edgeBlocks, 256, 0, stream>>>(dst, deg, E);
    bsum_kernel<<<nb, 256, 0, stream>>>(deg, bsum, n);
    bscan_kernel<<<1, 1024, 0, stream>>>(bsum, bexcl, nb, off, n);
    off_kernel<<<nb, 256, 0, stream>>>(deg, bexcl, off, cursor, n);
    fill_kernel<<<edgeBlocks, 256, 0, stream>>>(src, dst, cursor, csr_src, E);
    convert_xb_kernel<<<cvBlocks, 256, 0, stream>>>(x, xb, n, cvTotal);

    // ---------- layer 1 ----------
    proj_mfma_kernel<<<nblk, 256, 0, stream>>>(xb, wf, bq1, bk1, bv1, bs1,
                                               qb, kvb, sp, n);
    attn_ln_kernel<<<nodeBlocks, 256, 0, stream>>>((const uint4*)qb,
                                                   (const uint4*)kvb,
                                                   (const float4*)sp,
                                                   off, csr_src,
                                                   (const float4*)g1, (const float4*)be1,
                                                   nullptr, (uint4*)hb, n, 1);

    // ---------- layer 2 ----------
    proj_mfma_kernel<<<nblk, 256, 0, stream>>>(hb, wf + (size_t)4 * 16384,
                                               bq2, bk2, bv2, bs2,
                                               qb, kvb, sp, n);
    attn_ln_kernel<<<nodeBlocks, 256, 0, stream>>>((const uint4*)qb,
                                                   (const uint4*)kvb,
                                                   (const float4*)sp,
                                                   off, csr_src,
                                                   (const float4*)g2, (const float4*)be2,
                                                   (float4*)d_out, nullptr, n, 0);
}

// Round 8
// 293.142 us; speedup vs baseline: 11.7911x; 1.0264x over previous
//
#include <hip/hip_runtime.h>
#include <math.h>

#define LN_EPS 1e-5f
#define ATT_SCALE 0.17677669529663687f   // 1/sqrt(32)

typedef __attribute__((ext_vector_type(8))) short bf16x8;
typedef __attribute__((ext_vector_type(4))) float f32x4;
typedef __attribute__((ext_vector_type(2))) _Float16 half2_t;

__device__ __forceinline__ unsigned short f2b(float f) {
    unsigned u = __float_as_uint(f);
    unsigned r = (u + 0x7FFFu + ((u >> 16) & 1)) >> 16;   // RNE
    return (unsigned short)r;
}
__device__ __forceinline__ half2_t bc(unsigned u) {
    return __builtin_bit_cast(half2_t, u);
}

// ---- convert fp32 [n][128] -> bf16 row-major [padrows][128], zero-padded ----
__global__ __launch_bounds__(256) void convert_xb_kernel(
    const float* __restrict__ x, unsigned short* __restrict__ xb,
    int n, int total)
{
    int t = blockIdx.x * 256 + threadIdx.x;
    if (t >= total) return;
    int r = t >> 4, c = t & 15;
    union { bf16x8 vec; unsigned short u[8]; } o;
    if (r < n) {
        float4 a = *(const float4*)(x + (size_t)r * 128 + c * 8);
        float4 b = *(const float4*)(x + (size_t)r * 128 + c * 8 + 4);
        o.u[0]=f2b(a.x); o.u[1]=f2b(a.y); o.u[2]=f2b(a.z); o.u[3]=f2b(a.w);
        o.u[4]=f2b(b.x); o.u[5]=f2b(b.y); o.u[6]=f2b(b.z); o.u[7]=f2b(b.w);
    } else {
        #pragma unroll
        for (int j = 0; j < 8; ++j) o.u[j] = 0;
    }
    *(bf16x8*)(xb + (size_t)r * 128 + c * 8) = o.vec;
}

// ---- convert 8 weight matrices -> B-fragment order wf[mi][cb][t][lane][8] ----
__global__ __launch_bounds__(256) void convert_w_kernel(
    const float* __restrict__ W0, const float* __restrict__ W1,
    const float* __restrict__ W2, const float* __restrict__ W3,
    const float* __restrict__ W4, const float* __restrict__ W5,
    const float* __restrict__ W6, const float* __restrict__ W7,
    unsigned short* __restrict__ wf)
{
    int t = blockIdx.x * 256 + threadIdx.x;
    if (t >= 16384) return;
    int mi = t >> 11, cb = (t >> 8) & 7, tk = (t >> 6) & 3, lane = t & 63;
    const float* W;
    switch (mi) {
        case 0: W = W0; break; case 1: W = W1; break;
        case 2: W = W2; break; case 3: W = W3; break;
        case 4: W = W4; break; case 5: W = W5; break;
        case 6: W = W6; break; default: W = W7; break;
    }
    int hi = lane >> 4, c = lane & 15;
    int col = cb * 16 + c;
    union { bf16x8 vec; unsigned short u[8]; } o;
    #pragma unroll
    for (int j = 0; j < 8; ++j) {
        int k = tk * 32 + hi * 8 + j;
        o.u[j] = f2b(W[k * 128 + col]);
    }
    *(bf16x8*)(wf + (size_t)t * 8) = o.vec;
}

// ---- fused 4-matrix MFMA projection; q f16, k/v halves f16, sp fp32 ----
__global__ __launch_bounds__(256) void proj_mfma_kernel(
    const unsigned short* __restrict__ xb, const unsigned short* __restrict__ wf,
    const float* __restrict__ b0, const float* __restrict__ b1,
    const float* __restrict__ b2, const float* __restrict__ b3,
    _Float16* __restrict__ qh, _Float16* __restrict__ kvh,
    float* __restrict__ spout, int n)
{
    const float* biases[4] = {b0, b1, b2, b3};
    int wave = threadIdx.x >> 6, lane = threadIdx.x & 63;
    int rb0 = (blockIdx.x * 4 + wave) * 2;
    int rr = lane & 15, hi = lane >> 4;

    bf16x8 af[2][4];
    #pragma unroll
    for (int rb2 = 0; rb2 < 2; ++rb2) {
        int row = (rb0 + rb2) * 16 + rr;
        #pragma unroll
        for (int t = 0; t < 4; ++t)
            af[rb2][t] = *(const bf16x8*)(xb + (size_t)row * 128 + t * 32 + hi * 8);
    }

    int c = lane & 15, rowg = (lane >> 4) * 4;
    int r0 = rb0 * 16 + rowg;

    #pragma unroll
    for (int mi = 0; mi < 4; ++mi) {
        const bf16x8* wfv = (const bf16x8*)(wf + (size_t)mi * 16384);
        const float* bias = biases[mi];
        #pragma unroll
        for (int cb = 0; cb < 8; ++cb) {
            f32x4 acc0 = {0.f, 0.f, 0.f, 0.f};
            f32x4 acc1 = {0.f, 0.f, 0.f, 0.f};
            #pragma unroll
            for (int t = 0; t < 4; ++t) {
                bf16x8 bfr = wfv[(cb * 4 + t) * 64 + lane];
                acc0 = __builtin_amdgcn_mfma_f32_16x16x32_bf16(af[0][t], bfr, acc0, 0, 0, 0);
                acc1 = __builtin_amdgcn_mfma_f32_16x16x32_bf16(af[1][t], bfr, acc1, 0, 0, 0);
            }
            int col = cb * 16 + c;
            float bb = bias[col];
            #pragma unroll
            for (int reg = 0; reg < 4; ++reg) {
                #pragma unroll
                for (int half = 0; half < 2; ++half) {
                    int ra = r0 + reg + half * 16;
                    if (ra >= n) continue;
                    float val = (half ? acc1[reg] : acc0[reg]) + bb;
                    if (mi == 0)      qh[(size_t)ra * 128 + col] = (_Float16)val;
                    else if (mi == 3) spout[(size_t)ra * 128 + col] = val;
                    else if (mi == 1) kvh[(size_t)ra * 256 + col]       = (_Float16)val;
                    else              kvh[(size_t)ra * 256 + 128 + col] = (_Float16)val;
                }
            }
        }
    }
}

// ---- CSR build: degree histogram ----
__global__ __launch_bounds__(256) void deg_kernel(
    const int* __restrict__ dst, int* __restrict__ deg, int E)
{
    for (int e = blockIdx.x * blockDim.x + threadIdx.x; e < E;
         e += gridDim.x * blockDim.x)
        atomicAdd(&deg[dst[e]], 1);
}

// ---- device-wide 3-pass exclusive scan ----
__global__ __launch_bounds__(256) void bsum_kernel(
    const int* __restrict__ deg, int* __restrict__ bsum, int n)
{
    int i = blockIdx.x * 256 + threadIdx.x;
    int v = (i < n) ? deg[i] : 0;
    #pragma unroll
    for (int o = 32; o; o >>= 1) v += __shfl_xor(v, o);
    __shared__ int ws[4];
    int wave = threadIdx.x >> 6, lane = threadIdx.x & 63;
    if (lane == 0) ws[wave] = v;
    __syncthreads();
    if (threadIdx.x == 0) bsum[blockIdx.x] = ws[0] + ws[1] + ws[2] + ws[3];
}

__global__ __launch_bounds__(1024) void bscan_kernel(
    const int* __restrict__ bsum, int* __restrict__ bexcl,
    int nb, int* __restrict__ off, int n)
{
    int t = threadIdx.x;
    int v = (t < nb) ? bsum[t] : 0;
    int orig = v;
    int lane = t & 63, wave = t >> 6;
    #pragma unroll
    for (int o = 1; o < 64; o <<= 1) {
        int up = __shfl_up(v, o);
        if (lane >= o) v += up;
    }
    __shared__ int ws[16];
    if (lane == 63) ws[wave] = v;
    __syncthreads();
    int pre = 0;
    for (int wv = 0; wv < wave; ++wv) pre += ws[wv];
    int incl = v + pre;
    if (t < nb) bexcl[t] = incl - orig;
    if (t == nb - 1) off[n] = incl;
}

__global__ __launch_bounds__(256) void off_kernel(
    const int* __restrict__ deg, const int* __restrict__ bexcl,
    int* __restrict__ off, int* __restrict__ cursor, int n)
{
    int i = blockIdx.x * 256 + threadIdx.x;
    int v = (i < n) ? deg[i] : 0;
    int orig = v;
    int lane = threadIdx.x & 63, wave = threadIdx.x >> 6;
    #pragma unroll
    for (int o = 1; o < 64; o <<= 1) {
        int up = __shfl_up(v, o);
        if (lane >= o) v += up;
    }
    __shared__ int ws[4];
    if (lane == 63) ws[wave] = v;
    __syncthreads();
    int pre = bexcl[blockIdx.x];
    for (int wv = 0; wv < wave; ++wv) pre += ws[wv];
    if (i < n) {
        int ex = pre + v - orig;
        off[i] = ex;
        cursor[i] = ex;
    }
}

__global__ __launch_bounds__(256) void fill_kernel(
    const int* __restrict__ src, const int* __restrict__ dst,
    int* __restrict__ cursor, int* __restrict__ csr_src, int E)
{
    for (int e = blockIdx.x * blockDim.x + threadIdx.x; e < E;
         e += gridDim.x * blockDim.x) {
        int d = dst[e];
        int p = atomicAdd(&cursor[d], 1);
        csr_src[p] = src[e];
    }
}

// ---- fused attention + defer-max softmax + skip + LN; one wave/node ----
// 4 slots x 16 lanes; lane owns 8 dims; head = 4 lanes; f16 dot2 for q.k.
__global__ __launch_bounds__(256) void attn_ln_kernel(
    const uint4* __restrict__ qh4,     // [n][16] uint4 = 128 f16/row
    const uint4* __restrict__ kv4,     // [n][32] uint4: 16 k-words + 16 v-words
    const float4* __restrict__ sp4,    // [n][32] float4
    const int* __restrict__ off, const int* __restrict__ csr_src,
    const float4* __restrict__ g4, const float4* __restrict__ b4,
    float4* __restrict__ outf, uint4* __restrict__ outb,
    int n, int relu)
{
    int node = blockIdx.x * 4 + (threadIdx.x >> 6);
    if (node >= n) return;
    int lane = threadIdx.x & 63;
    int slot = lane >> 4, ll = lane & 15;

    uint4 qw = qh4[(size_t)node * 16 + ll];   // packed f16, consumed by dot2

    int e0 = off[node], e1 = off[node + 1];
    int cnt = e1 - e0;
    int T = (cnt + 3) >> 2;

    float m = -1e30f, ss = 0.f;   // m is a softmax ANCHOR (defer-max), not true max
    float a[8];
    #pragma unroll
    for (int j = 0; j < 8; ++j) a[j] = 0.f;

    int idx = e0 + slot;
    int vA = (idx < e1);
    int sA = vA ? csr_src[idx] : 0;
    uint4 kA = kv4[(size_t)sA * 32 + ll];
    uint4 vA4 = kv4[(size_t)sA * 32 + 16 + ll];

    for (int t = 0; t < T; ++t) {
        int nidx = idx + 4;
        int vN = (nidx < e1);
        int sN = vN ? csr_src[nidx] : 0;
        uint4 kN = kv4[(size_t)sN * 32 + ll];
        uint4 vN4 = kv4[(size_t)sN * 32 + 16 + ll];

        float dot = 0.f;
        dot = __builtin_amdgcn_fdot2(bc(kA.x), bc(qw.x), dot, false);
        dot = __builtin_amdgcn_fdot2(bc(kA.y), bc(qw.y), dot, false);
        dot = __builtin_amdgcn_fdot2(bc(kA.z), bc(qw.z), dot, false);
        dot = __builtin_amdgcn_fdot2(bc(kA.w), bc(qw.w), dot, false);
        dot += __shfl_xor(dot, 1);     // reduce over the head's 4 lanes
        dot += __shfl_xor(dot, 2);

        float al = vA ? dot * ATT_SCALE : -1e38f;
        float d = al - m;
        if (__any(d > 20.f)) {         // rare: once per node, then never (logits small)
            float mn = fmaxf(m, al);
            float c = __expf(m - mn);
            ss *= c;
            #pragma unroll
            for (int j = 0; j < 8; ++j) a[j] *= c;
            m = mn;
            d = al - m;
        }
        float w = __expf(d);           // d <= 20 guaranteed; invalid edges -> w = 0
        ss += w;
        half2_t p0 = bc(vA4.x), p1 = bc(vA4.y), p2 = bc(vA4.z), p3 = bc(vA4.w);
        a[0] = fmaf(w, (float)p0[0], a[0]); a[1] = fmaf(w, (float)p0[1], a[1]);
        a[2] = fmaf(w, (float)p1[0], a[2]); a[3] = fmaf(w, (float)p1[1], a[3]);
        a[4] = fmaf(w, (float)p2[0], a[4]); a[5] = fmaf(w, (float)p2[1], a[5]);
        a[6] = fmaf(w, (float)p3[0], a[6]); a[7] = fmaf(w, (float)p3[1], a[7]);

        idx = nidx; vA = vN; kA = kN; vA4 = vN4;
    }

    // combine the 4 slots' anchored-softmax states (flash merge; valid for any anchor)
    float mg = m;
    mg = fmaxf(mg, __shfl_xor(mg, 16));
    mg = fmaxf(mg, __shfl_xor(mg, 32));
    float sc = __expf(m - mg);          // 0 for empty slots (m = -1e30)
    float ssg = ss * sc;
    ssg += __shfl_xor(ssg, 16);
    ssg += __shfl_xor(ssg, 32);
    #pragma unroll
    for (int j = 0; j < 8; ++j) {
        float aj = a[j] * sc;
        aj += __shfl_xor(aj, 16);
        aj += __shfl_xor(aj, 32);
        a[j] = aj;
    }

    float inv = (ssg > 0.f) ? 1.f / ssg : 0.f;
    float4 s0 = sp4[(size_t)node * 32 + 2 * ll];
    float4 s1 = sp4[(size_t)node * 32 + 2 * ll + 1];
    float o[8];
    o[0]=fmaf(a[0],inv,s0.x); o[1]=fmaf(a[1],inv,s0.y);
    o[2]=fmaf(a[2],inv,s0.z); o[3]=fmaf(a[3],inv,s0.w);
    o[4]=fmaf(a[4],inv,s1.x); o[5]=fmaf(a[5],inv,s1.y);
    o[6]=fmaf(a[6],inv,s1.z); o[7]=fmaf(a[7],inv,s1.w);

    // layernorm over 128 dims = 16 lanes x 8 (replicated across slots)
    float sum = o[0]+o[1]+o[2]+o[3]+o[4]+o[5]+o[6]+o[7];
    sum += __shfl_xor(sum, 1); sum += __shfl_xor(sum, 2);
    sum += __shfl_xor(sum, 4); sum += __shfl_xor(sum, 8);
    float mu = sum * (1.f / 128.f);
    float var = 0.f;
    float d8[8];
    #pragma unroll
    for (int j = 0; j < 8; ++j) { d8[j] = o[j] - mu; var = fmaf(d8[j], d8[j], var); }
    var += __shfl_xor(var, 1); var += __shfl_xor(var, 2);
    var += __shfl_xor(var, 4); var += __shfl_xor(var, 8);
    float rstd = rsqrtf(var * (1.f / 128.f) + LN_EPS);

    float4 gg0 = g4[2 * ll], gg1 = g4[2 * ll + 1];
    float4 bb0 = b4[2 * ll], bb1 = b4[2 * ll + 1];
    float r[8];
    r[0]=fmaf(d8[0]*rstd, gg0.x, bb0.x); r[1]=fmaf(d8[1]*rstd, gg0.y, bb0.y);
    r[2]=fmaf(d8[2]*rstd, gg0.z, bb0.z); r[3]=fmaf(d8[3]*rstd, gg0.w, bb0.w);
    r[4]=fmaf(d8[4]*rstd, gg1.x, bb1.x); r[5]=fmaf(d8[5]*rstd, gg1.y, bb1.y);
    r[6]=fmaf(d8[6]*rstd, gg1.z, bb1.z); r[7]=fmaf(d8[7]*rstd, gg1.w, bb1.w);

    if (slot == 0) {
        if (relu) {
            #pragma unroll
            for (int j = 0; j < 8; ++j) r[j] = fmaxf(r[j], 0.f);
            uint4 ow;
            ow.x = (unsigned)f2b(r[0]) | ((unsigned)f2b(r[1]) << 16);
            ow.y = (unsigned)f2b(r[2]) | ((unsigned)f2b(r[3]) << 16);
            ow.z = (unsigned)f2b(r[4]) | ((unsigned)f2b(r[5]) << 16);
            ow.w = (unsigned)f2b(r[6]) | ((unsigned)f2b(r[7]) << 16);
            outb[(size_t)node * 16 + ll] = ow;
        } else {
            outf[(size_t)node * 32 + 2 * ll]     = make_float4(r[0], r[1], r[2], r[3]);
            outf[(size_t)node * 32 + 2 * ll + 1] = make_float4(r[4], r[5], r[6], r[7]);
        }
    }
}

extern "C" void kernel_launch(void* const* d_in, const int* in_sizes, int n_in,
                              void* d_out, int out_size, void* d_ws, size_t ws_size,
                              hipStream_t stream) {
    const float* x  = (const float*)d_in[0];
    const int*   ei = (const int*)d_in[1];
    const int n = in_sizes[0] / 128;
    const int E = in_sizes[1] / 2;
    const int* src = ei;
    const int* dst = ei + E;

    const float *Wq1 = (const float*)d_in[2],  *bq1 = (const float*)d_in[3];
    const float *Wk1 = (const float*)d_in[4],  *bk1 = (const float*)d_in[5];
    const float *Wv1 = (const float*)d_in[6],  *bv1 = (const float*)d_in[7];
    const float *Ws1 = (const float*)d_in[8],  *bs1 = (const float*)d_in[9];
    const float *g1  = (const float*)d_in[10], *be1 = (const float*)d_in[11];
    const float *Wq2 = (const float*)d_in[12], *bq2 = (const float*)d_in[13];
    const float *Wk2 = (const float*)d_in[14], *bk2 = (const float*)d_in[15];
    const float *Wv2 = (const float*)d_in[16], *bv2 = (const float*)d_in[17];
    const float *Ws2 = (const float*)d_in[18], *bs2 = (const float*)d_in[19];
    const float *g2  = (const float*)d_in[20], *be2 = (const float*)d_in[21];

    // geometry
    const int nrb     = (n + 15) / 16;
    const int nblk    = (nrb + 7) / 8;
    const int padrows = nblk * 8 * 16;
    const int nb      = (n + 255) / 256;

    // workspace layout
    const size_t nf = (size_t)n * 128;
    char* w = (char*)d_ws;
    float* sp = (float*)w; w += nf * sizeof(float);
    _Float16* qh  = (_Float16*)w; w += nf * sizeof(_Float16);
    _Float16* kvh = (_Float16*)w; w += (size_t)n * 256 * sizeof(_Float16);
    unsigned short* xb  = (unsigned short*)w; w += (size_t)padrows * 128 * sizeof(unsigned short);
    unsigned short* hb  = (unsigned short*)w; w += (size_t)padrows * 128 * sizeof(unsigned short);
    unsigned short* wf  = (unsigned short*)w; w += (size_t)8 * 16384 * sizeof(unsigned short);
    int* deg     = (int*)w; w += (size_t)(n + 1) * sizeof(int);
    int* off     = (int*)w; w += (size_t)(n + 1) * sizeof(int);
    int* cursor  = (int*)w; w += (size_t)(n + 1) * sizeof(int);
    int* bsum    = (int*)w; w += (size_t)nb * sizeof(int);
    int* bexcl   = (int*)w; w += (size_t)nb * sizeof(int);
    int* csr_src = (int*)w; w += (size_t)E * sizeof(int);

    int edgeBlocks = (E + 255) / 256; if (edgeBlocks > 2048) edgeBlocks = 2048;
    int nodeBlocks = (n + 3) / 4;
    int cvTotal  = padrows * 16;
    int cvBlocks = (cvTotal + 255) / 256;

    // ---------- one-time prep ----------
    convert_w_kernel<<<64, 256, 0, stream>>>(Wq1, Wk1, Wv1, Ws1, Wq2, Wk2, Wv2, Ws2, wf);
    hipMemsetAsync(deg, 0, (size_t)n * sizeof(int), stream);
    deg_kernel<<<edgeBlocks, 256, 0, stream>>>(dst, deg, E);
    bsum_kernel<<<nb, 256, 0, stream>>>(deg, bsum, n);
    bscan_kernel<<<1, 1024, 0, stream>>>(bsum, bexcl, nb, off, n);
    off_kernel<<<nb, 256, 0, stream>>>(deg, bexcl, off, cursor, n);
    fill_kernel<<<edgeBlocks, 256, 0, stream>>>(src, dst, cursor, csr_src, E);
    convert_xb_kernel<<<cvBlocks, 256, 0, stream>>>(x, xb, n, cvTotal);

    // ---------- layer 1 ----------
    proj_mfma_kernel<<<nblk, 256, 0, stream>>>(xb, wf, bq1, bk1, bv1, bs1,
                                               qh, kvh, sp, n);
    attn_ln_kernel<<<nodeBlocks, 256, 0, stream>>>((const uint4*)qh,
                                                   (const uint4*)kvh,
                                                   (const float4*)sp,
                                                   off, csr_src,
                                                   (const float4*)g1, (const float4*)be1,
                                                   nullptr, (uint4*)hb, n, 1);

    // ---------- layer 2 ----------
    proj_mfma_kernel<<<nblk, 256, 0, stream>>>(hb, wf + (size_t)4 * 16384,
                                               bq2, bk2, bv2, bs2,
                                               qh, kvh, sp, n);
    attn_ln_kernel<<<nodeBlocks, 256, 0, stream>>>((const uint4*)qh,
                                                   (const uint4*)kvh,
                                                   (const float4*)sp,
                                                   off, csr_src,
                                                   (const float4*)g2, (const float4*)be2,
                                                   (float4*)d_out, nullptr, n, 0);
}